// Round 3
// baseline (4530.349 us; speedup 1.0000x reference)
//
#include <hip/hip_runtime.h>
#include <stdint.h>
#include <stdio.h>

#define T_TOK 8192
#define HDIM  1024
#define IDIM  3584
#define NEXP  8
#define NPAIR (T_TOK*2)
#define BM 128
#define BN 128
#define BK 32

typedef float          f32x4 __attribute__((ext_vector_type(4)));
typedef short          s16x8 __attribute__((ext_vector_type(8)));
typedef unsigned short u16x4 __attribute__((ext_vector_type(4)));
typedef unsigned short u16x8 __attribute__((ext_vector_type(8)));

__device__ __forceinline__ unsigned short f2bf_rne(float f) {
  unsigned u = __float_as_uint(f);
  u += 0x7FFFu + ((u >> 16) & 1u);
  return (unsigned short)(u >> 16);
}
__device__ __forceinline__ float bf2f(unsigned short h) {
  return __uint_as_float(((unsigned)h) << 16);
}

__device__ __forceinline__ void gld16(const void* gsrc, void* ldst) {
  typedef const unsigned int __attribute__((address_space(1))) GU;
  typedef unsigned int       __attribute__((address_space(3))) LU;
  __builtin_amdgcn_global_load_lds((GU*)(unsigned long long)gsrc,
                                   (LU*)(unsigned int)(unsigned long long)ldst,
                                   16, 0, 0);
}

// ================= K1: split f32 -> (hi, lo) bf16 =================
__global__ void split_hilo(const float* __restrict__ in,
                           unsigned short* __restrict__ hi,
                           unsigned short* __restrict__ lo, int n4) {
  int i = blockIdx.x*blockDim.x + threadIdx.x;
  int s = gridDim.x*blockDim.x;
  for (; i < n4; i += s) {
    f32x4 v = ((const f32x4*)in)[i];
    u16x4 h, l;
#pragma unroll
    for (int j = 0; j < 4; j++) {
      float f = v[j];
      unsigned short hb = f2bf_rne(f);
      h[j] = hb;
      l[j] = f2bf_rne(f - bf2f(hb));
    }
    ((u16x4*)hi)[i] = h;
    ((u16x4*)lo)[i] = l;
  }
}

// ===== K2: transpose W [E][K][N] f32 -> Wt [E][N][K] bf16 hi (+lo optional)
__global__ void transpose_split(const float* __restrict__ W,
                                unsigned short* __restrict__ hi,
                                unsigned short* __restrict__ lo,
                                int K, int N) {
  __shared__ float tile[32][33];
  long base = (long)blockIdx.z * K * N;
  int n0 = blockIdx.x*32, k0 = blockIdx.y*32;
  int tx = threadIdx.x, ty = threadIdx.y; // 32 x 8
#pragma unroll
  for (int r = 0; r < 4; r++)
    tile[ty+8*r][tx] = W[base + (long)(k0+ty+8*r)*N + n0 + tx];
  __syncthreads();
#pragma unroll
  for (int r = 0; r < 4; r++) {
    float f = tile[tx][ty+8*r];
    long o = base + (long)(n0+ty+8*r)*K + k0 + tx;
    unsigned short hb = f2bf_rne(f);
    hi[o] = hb;
    if (lo) lo[o] = f2bf_rne(f - bf2f(hb));
  }
}

// ---- shared top-2 helper (stable, lowest-index tie-break like lax.top_k)
__device__ __forceinline__ void top2_write(const float* acc, int t,
                                           int* __restrict__ topi,
                                           float* __restrict__ topw) {
  int i0 = 0; float l0 = acc[0];
#pragma unroll
  for (int e = 1; e < NEXP; e++) if (acc[e] > l0) { l0 = acc[e]; i0 = e; }
  int i1 = -1; float l1 = -3.4e38f;
#pragma unroll
  for (int e = 0; e < NEXP; e++) if (e != i0 && acc[e] > l1) { l1 = acc[e]; i1 = e; }
  float w0 = 1.f/(1.f + expf(l1 - l0));
  float w1 = 1.f/(1.f + expf(l0 - l1));
  topi[2*t]   = i0; topi[2*t+1] = i1;
  topw[2*t]   = w0; topw[2*t+1] = w1;
}

// ===== K3: fused gate+up router (one pass over x) =========================
__global__ __launch_bounds__(256) void router2_topk(
    const float* __restrict__ X,
    const float* __restrict__ RWg, const float* __restrict__ RWu,
    int* __restrict__ tig, float* __restrict__ twg,
    int* __restrict__ tiu, float* __restrict__ twu) {
  int lane = threadIdx.x & 63;
  int t = blockIdx.x*4 + (threadIdx.x>>6);
  const f32x4* xr = (const f32x4*)(X + (long)t*HDIM);
  float ag[NEXP], au[NEXP];
#pragma unroll
  for (int e = 0; e < NEXP; e++) { ag[e] = 0.f; au[e] = 0.f; }
#pragma unroll
  for (int it = 0; it < HDIM/4/64; it++) {   // 4
    int c4 = it*64 + lane;
    f32x4 xv = xr[c4];
#pragma unroll
    for (int j = 0; j < 4; j++) {
      const float* wg = RWg + (long)(c4*4+j)*NEXP;
      const float* wu = RWu + (long)(c4*4+j)*NEXP;
#pragma unroll
      for (int e = 0; e < NEXP; e++) { ag[e] += xv[j]*wg[e]; au[e] += xv[j]*wu[e]; }
    }
  }
#pragma unroll
  for (int e = 0; e < NEXP; e++) {
    float vg = ag[e], vu = au[e];
#pragma unroll
    for (int o = 1; o < 64; o <<= 1) { vg += __shfl_xor(vg, o); vu += __shfl_xor(vu, o); }
    ag[e] = vg; au[e] = vu;
  }
  if (lane == 0) { top2_write(ag, t, tig, twg); top2_write(au, t, tiu, twu); }
}

// ===== K4: deterministic stable per-expert compaction (1 block per expert)
__global__ __launch_bounds__(256) void build_perm(const int* __restrict__ topi,
                                                  const float* __restrict__ topw,
                                                  int* __restrict__ offs,
                                                  int* __restrict__ ptok,
                                                  float* __restrict__ pw) {
  int e = blockIdx.x;
  int tid = threadIdx.x, lane = tid & 63, wv = tid >> 6;
  __shared__ int cnt[NEXP];
  __shared__ int wsum[4];
  if (tid < NEXP) cnt[tid] = 0;
  __syncthreads();
  for (int p = tid; p < NPAIR; p += 256) atomicAdd(&cnt[topi[p]], 1);
  __syncthreads();
  int base = 0;
#pragma unroll
  for (int e2 = 0; e2 < NEXP; e2++) if (e2 < e) base += cnt[e2];
  if (tid == 0) { offs[e] = base; if (e == NEXP-1) offs[NEXP] = base + cnt[e]; }
  for (int p0 = 0; p0 < NPAIR; p0 += 256) {
    int p = p0 + tid;
    bool m = (topi[p] == e);
    unsigned long long b = __ballot(m);
    int lp = __popcll(b & ((1ull << lane) - 1ull));
    if (lane == 0) wsum[wv] = __popcll(b);
    __syncthreads();
    int woff = 0;
#pragma unroll
    for (int w2 = 0; w2 < 4; w2++) if (w2 < wv) woff += wsum[w2];
    int tot = wsum[0] + wsum[1] + wsum[2] + wsum[3];
    if (m) { int dst = base + woff + lp; ptok[dst] = p >> 1; pw[dst] = topw[p]; }
    base += tot;
    __syncthreads();
  }
}

// ===== K5: gathered MoE GEMM, 4-term bf16 split, prefetch-dbuf 2-phase ====
__global__ __launch_bounds__(256) void moe_gemm4(
    const unsigned short* __restrict__ Ahi, const unsigned short* __restrict__ Alo,
    const unsigned short* __restrict__ Bhi, const unsigned short* __restrict__ Blo,
    const int* __restrict__ offs, const int* __restrict__ ptok,
    const float* __restrict__ pw, float* __restrict__ out, int K, int N)
{
  const int e = blockIdx.z;
  const int beg = offs[e];
  const int cnt = offs[e+1] - beg;
  // T1: XCD-aware bijective swizzle of the (m,n) tile id (nwg % 8 == 0)
  const int nwg = gridDim.x * gridDim.y;
  const int orig = blockIdx.y * gridDim.x + blockIdx.x;
  const int swz = (orig & 7) * (nwg >> 3) + (orig >> 3);
  const int m0 = (swz / gridDim.x) * BM;
  if (m0 >= cnt) return;
  const int n0 = (swz % gridDim.x) * BN;

  __shared__ unsigned short Ah[2][BM*BK], Al[2][BM*BK], Bh[2][BN*BK], Bl[2][BN*BK];
  __shared__ int   stok[BM];
  __shared__ float swt[BM];

  const int tid = threadIdx.x, lane = tid & 63, wv = tid >> 6;
  if (tid < BM) {
    int i = m0 + tid;
    stok[tid] = ptok[beg + (i < cnt ? i : 0)];
    swt[tid]  = (i < cnt) ? pw[beg + i] : 0.f;
  }
  __syncthreads();

  const int srow = lane >> 2;
  const int scol = (lane & 3) * 8;
  const int r0 = (wv*2+0)*16 + srow;
  const int r1 = (wv*2+1)*16 + srow;
  const long a0 = (long)stok[r0]*K + scol;
  const long a1 = (long)stok[r1]*K + scol;
  const long b0 = ((long)e*N + n0 + r0)*K + scol;
  const long b1 = ((long)e*N + n0 + r1)*K + scol;
  const int o0 = (wv*2+0)*16*BK;
  const int o1 = (wv*2+1)*16*BK;

#define STAGE4(buf, kk) do {                                     \
    gld16(Ahi + a0 + (kk), &Ah[buf][o0]);                        \
    gld16(Ahi + a1 + (kk), &Ah[buf][o1]);                        \
    gld16(Alo + a0 + (kk), &Al[buf][o0]);                        \
    gld16(Alo + a1 + (kk), &Al[buf][o1]);                        \
    gld16(Bhi + b0 + (kk), &Bh[buf][o0]);                        \
    gld16(Bhi + b1 + (kk), &Bh[buf][o1]);                        \
    gld16(Blo + b0 + (kk), &Bl[buf][o0]);                        \
    gld16(Blo + b1 + (kk), &Bl[buf][o1]);                        \
  } while (0)

  f32x4 zero = {0.f, 0.f, 0.f, 0.f};
  f32x4 acc[4][4];
#pragma unroll
  for (int i = 0; i < 4; i++)
#pragma unroll
    for (int j = 0; j < 4; j++) acc[i][j] = zero;

  const int arow = (wv>>1)*64, bcol = (wv&1)*64;
  const int fl = lane & 15, fg = lane >> 4;

  STAGE4(0, 0);
  asm volatile("s_waitcnt vmcnt(0)" ::: "memory");
  __syncthreads();

  int cur = 0;
  for (int kk = 0; kk < K; kk += BK) {
    if (kk + BK < K) STAGE4(cur^1, kk + BK);   // prefetch next tile (in flight over MFMA)

    s16x8 ahf[4], alf[4], bhf[4], blf[4];
#pragma unroll
    for (int i = 0; i < 4; i++) {
      ahf[i] = *(const s16x8*)&Ah[cur][(arow + i*16 + fl)*BK + fg*8];
      alf[i] = *(const s16x8*)&Al[cur][(arow + i*16 + fl)*BK + fg*8];
      bhf[i] = *(const s16x8*)&Bh[cur][(bcol + i*16 + fl)*BK + fg*8];
      blf[i] = *(const s16x8*)&Bl[cur][(bcol + i*16 + fl)*BK + fg*8];
    }
#pragma unroll
    for (int i = 0; i < 4; i++)
#pragma unroll
      for (int j = 0; j < 4; j++) {
        acc[i][j] = __builtin_amdgcn_mfma_f32_16x16x32_bf16(ahf[i], bhf[j], acc[i][j], 0,0,0);
        acc[i][j] = __builtin_amdgcn_mfma_f32_16x16x32_bf16(alf[i], bhf[j], acc[i][j], 0,0,0);
        acc[i][j] = __builtin_amdgcn_mfma_f32_16x16x32_bf16(ahf[i], blf[j], acc[i][j], 0,0,0);
        acc[i][j] = __builtin_amdgcn_mfma_f32_16x16x32_bf16(alf[i], blf[j], acc[i][j], 0,0,0);
      }

    asm volatile("s_waitcnt vmcnt(0)" ::: "memory");  // prefetch landed
    __syncthreads();                                  // everyone done reading cur
    cur ^= 1;
  }
#undef STAGE4

  // epilogue: C/D map col=lane&15, row=(lane>>4)*4+r  [m89/m91-verified]
#pragma unroll
  for (int i = 0; i < 4; i++)
#pragma unroll
    for (int r = 0; r < 4; r++) {
      int lrow = arow + i*16 + fg*4 + r;
      if (m0 + lrow < cnt) {
        float wt = swt[lrow];
        long ob = (long)stok[lrow]*N + n0 + bcol + fl;
#pragma unroll
        for (int j = 0; j < 4; j++)
          atomicAdd(&out[ob + j*16], wt * acc[i][j][r]);
      }
    }
}

// ===== K6: fused SwiGLU + down-router (h in-place into g, one pass) =======
__global__ __launch_bounds__(256) void swiglu_router(
    float* __restrict__ g, const float* __restrict__ u,
    const float* __restrict__ RW,           // down router [IDIM][NEXP]
    int* __restrict__ topi, float* __restrict__ topw) {
  int lane = threadIdx.x & 63;
  int t = blockIdx.x*4 + (threadIdx.x>>6);
  f32x4*       gr = (f32x4*)(g + (long)t*IDIM);
  const f32x4* ur = (const f32x4*)(u + (long)t*IDIM);
  float acc[NEXP];
#pragma unroll
  for (int e = 0; e < NEXP; e++) acc[e] = 0.f;
#pragma unroll
  for (int it = 0; it < IDIM/4/64; it++) {   // 14
    int c4 = it*64 + lane;
    f32x4 gv = gr[c4], uv = ur[c4], hv;
#pragma unroll
    for (int j = 0; j < 4; j++) {
      float x = gv[j];
      hv[j] = x * uv[j] / (1.f + expf(-x));
    }
    gr[c4] = hv;
#pragma unroll
    for (int j = 0; j < 4; j++) {
      const float* wr = RW + (long)(c4*4+j)*NEXP;
#pragma unroll
      for (int e = 0; e < NEXP; e++) acc[e] += hv[j]*wr[e];
    }
  }
#pragma unroll
  for (int e = 0; e < NEXP; e++) {
    float v = acc[e];
#pragma unroll
    for (int o = 1; o < 64; o <<= 1) v += __shfl_xor(v, o);
    acc[e] = v;
  }
  if (lane == 0) top2_write(acc, t, topi, topw);
}

// ===== K7: down GEMM: A = h f32 (reg-staged split), B = Wd_hi bf16 ========
__global__ __launch_bounds__(256) void moe_gemm_down(
    const float* __restrict__ Hf, const unsigned short* __restrict__ Bw,
    const int* __restrict__ offs, const int* __restrict__ ptok,
    const float* __restrict__ pw, float* __restrict__ out)
{
  const int K = IDIM, N = HDIM;
  const int e = blockIdx.z;
  const int beg = offs[e];
  const int cnt = offs[e+1] - beg;
  const int nwg = gridDim.x * gridDim.y;
  const int orig = blockIdx.y * gridDim.x + blockIdx.x;
  const int swz = (orig & 7) * (nwg >> 3) + (orig >> 3);
  const int m0 = (swz / gridDim.x) * BM;
  if (m0 >= cnt) return;
  const int n0 = (swz % gridDim.x) * BN;

  __shared__ unsigned short Ah[2][BM*BK], Al[2][BM*BK], Bh[2][BN*BK];
  __shared__ int   stok[BM];
  __shared__ float swt[BM];

  const int tid = threadIdx.x, lane = tid & 63, wv = tid >> 6;
  if (tid < BM) {
    int i = m0 + tid;
    stok[tid] = ptok[beg + (i < cnt ? i : 0)];
    swt[tid]  = (i < cnt) ? pw[beg + i] : 0.f;
  }
  __syncthreads();

  // A path: each thread owns half a row (16 f32 -> 16 bf16 hi + 16 lo)
  const int arw = tid >> 1, half = tid & 1;
  const float* asrc = Hf + (long)stok[arw]*K + half*16;
  const int awoff = arw*BK + half*16;

  // B path: gld16 staging
  const int srow = lane >> 2, scol = (lane & 3)*8;
  const int r0 = (wv*2+0)*16 + srow, r1 = (wv*2+1)*16 + srow;
  const long b0 = ((long)e*N + n0 + r0)*K + scol;
  const long b1 = ((long)e*N + n0 + r1)*K + scol;
  const int o0 = (wv*2+0)*16*BK, o1 = (wv*2+1)*16*BK;

  f32x4 p0, p1, p2, p3;
  u16x8 ha, la, hb2, lb2;

#define LOADA(kk) do {                        \
    p0 = ((const f32x4*)(asrc + (kk)))[0];    \
    p1 = ((const f32x4*)(asrc + (kk)))[1];    \
    p2 = ((const f32x4*)(asrc + (kk)))[2];    \
    p3 = ((const f32x4*)(asrc + (kk)))[3];    \
  } while (0)
#define SP1(F,HV,LV,IX) { float _f=(F); unsigned short _h=f2bf_rne(_f); HV[IX]=_h; LV[IX]=f2bf_rne(_f - bf2f(_h)); }
#define CVTWR(buf) do {                                                   \
    SP1(p0[0],ha,la,0) SP1(p0[1],ha,la,1) SP1(p0[2],ha,la,2) SP1(p0[3],ha,la,3) \
    SP1(p1[0],ha,la,4) SP1(p1[1],ha,la,5) SP1(p1[2],ha,la,6) SP1(p1[3],ha,la,7) \
    SP1(p2[0],hb2,lb2,0) SP1(p2[1],hb2,lb2,1) SP1(p2[2],hb2,lb2,2) SP1(p2[3],hb2,lb2,3) \
    SP1(p3[0],hb2,lb2,4) SP1(p3[1],hb2,lb2,5) SP1(p3[2],hb2,lb2,6) SP1(p3[3],hb2,lb2,7) \
    *(u16x8*)&Ah[buf][awoff]     = ha;  *(u16x8*)&Ah[buf][awoff+8] = hb2; \
    *(u16x8*)&Al[buf][awoff]     = la;  *(u16x8*)&Al[buf][awoff+8] = lb2; \
  } while (0)
#define STAGEB(buf, kk) do {                  \
    gld16(Bw + b0 + (kk), &Bh[buf][o0]);      \
    gld16(Bw + b1 + (kk), &Bh[buf][o1]);      \
  } while (0)

  f32x4 zero = {0.f,0.f,0.f,0.f};
  f32x4 acc[4][4];
#pragma unroll
  for (int i = 0; i < 4; i++)
#pragma unroll
    for (int j = 0; j < 4; j++) acc[i][j] = zero;

  const int arow = (wv>>1)*64, bcol = (wv&1)*64;
  const int fl = lane & 15, fg = lane >> 4;

  // prologue: stage tile 0
  LOADA(0);
  STAGEB(0, 0);
  CVTWR(0);
  asm volatile("s_waitcnt vmcnt(0)" ::: "memory");
  __syncthreads();

  int cur = 0;
  for (int kk = 0; kk < K; kk += BK) {
    const bool nx = (kk + BK < K);
    if (nx) { LOADA(kk + BK); STAGEB(cur^1, kk + BK); }  // issue early (T14)

    s16x8 ahf[4], alf[4], bhf[4];
#pragma unroll
    for (int i = 0; i < 4; i++) {
      ahf[i] = *(const s16x8*)&Ah[cur][(arow + i*16 + fl)*BK + fg*8];
      alf[i] = *(const s16x8*)&Al[cur][(arow + i*16 + fl)*BK + fg*8];
      bhf[i] = *(const s16x8*)&Bh[cur][(bcol + i*16 + fl)*BK + fg*8];
    }
#pragma unroll
    for (int i = 0; i < 4; i++)
#pragma unroll
      for (int j = 0; j < 4; j++) {
        acc[i][j] = __builtin_amdgcn_mfma_f32_16x16x32_bf16(ahf[i], bhf[j], acc[i][j], 0,0,0);
        acc[i][j] = __builtin_amdgcn_mfma_f32_16x16x32_bf16(alf[i], bhf[j], acc[i][j], 0,0,0);
      }

    if (nx) CVTWR(cur^1);                     // write-late after compute
    asm volatile("s_waitcnt vmcnt(0)" ::: "memory");
    __syncthreads();
    cur ^= 1;
  }
#undef LOADA
#undef SP1
#undef CVTWR
#undef STAGEB

#pragma unroll
  for (int i = 0; i < 4; i++)
#pragma unroll
    for (int r = 0; r < 4; r++) {
      int lrow = arow + i*16 + fg*4 + r;
      if (m0 + lrow < cnt) {
        float wt = swt[lrow];
        long ob = (long)stok[lrow]*N + n0 + bcol + fl;
#pragma unroll
        for (int j = 0; j < 4; j++)
          atomicAdd(&out[ob + j*16], wt * acc[i][j][r]);
      }
    }
}

// ========================== host launcher =================================
// Workspace aliasing (448 MiB avail, peak ~387 MB):
//   ubuf  aliases [wg_hi, wg_lo] — first written AFTER gate GEMM (last wg reader)
//   wd_hi aliases [wu_hi, ...]   — transposed AFTER up GEMM (last wu reader)
extern "C" void kernel_launch(void* const* d_in, const int* in_sizes, int n_in,
                              void* d_out, int out_size, void* d_ws, size_t ws_size,
                              hipStream_t stream)
{
  (void)in_sizes; (void)n_in;
  const float* x   = (const float*)d_in[0];
  const float* grt = (const float*)d_in[1];
  const float* gex = (const float*)d_in[2];
  const float* urt = (const float*)d_in[3];
  const float* uex = (const float*)d_in[4];
  const float* drt = (const float*)d_in[5];
  const float* dex = (const float*)d_in[6];
  float* out = (float*)d_out;

  char* base = (char*)d_ws;
  size_t off = 0;
  auto alloc = [&](size_t b) -> void* {
    void* r = base + off;
    off = (off + b + 255) & ~(size_t)255;
    return r;
  };
  const size_t szXH = (size_t)T_TOK*HDIM*2;
  const size_t szW  = (size_t)NEXP*HDIM*IDIM*2;
  const size_t szGI = (size_t)T_TOK*IDIM*4;

  unsigned short* xhi   = (unsigned short*)alloc(szXH);
  unsigned short* xlo   = (unsigned short*)alloc(szXH);
  unsigned short* wg_hi = (unsigned short*)alloc(szW);   // later: ubuf (f32)
  unsigned short* wg_lo = (unsigned short*)alloc(szW);
  unsigned short* wu_hi = (unsigned short*)alloc(szW);   // later: wd_hi
  unsigned short* wu_lo = (unsigned short*)alloc(szW);
  float* gbuf = (float*)alloc(szGI);
  int*   topi_g = (int*)alloc(NPAIR*4);  float* topw_g = (float*)alloc(NPAIR*4);
  int*   topi_u = (int*)alloc(NPAIR*4);  float* topw_u = (float*)alloc(NPAIR*4);
  int*   topi_d = (int*)alloc(NPAIR*4);  float* topw_d = (float*)alloc(NPAIR*4);
  int* offs_g = (int*)alloc(64);
  int* offs_u = (int*)alloc(64);
  int* offs_d = (int*)alloc(64);
  int*   ptok_g = (int*)alloc(NPAIR*4);  float* pw_g = (float*)alloc(NPAIR*4);
  int*   ptok_u = (int*)alloc(NPAIR*4);  float* pw_u = (float*)alloc(NPAIR*4);
  int*   ptok_d = (int*)alloc(NPAIR*4);  float* pw_d = (float*)alloc(NPAIR*4);

  float*          ubuf  = (float*)wg_hi;
  unsigned short* wd_hi = wu_hi;

  if (off > ws_size) {
    fprintf(stderr, "[moe] ws too small: need %zu bytes, have %zu\n", off, ws_size);
    hipMemsetAsync(d_out, 0, (size_t)out_size*sizeof(float), stream);
    return;
  }

  hipMemsetAsync(gbuf, 0, szGI, stream);
  hipMemsetAsync(d_out, 0, (size_t)out_size*sizeof(float), stream);

  split_hilo<<<2048, 256, 0, stream>>>(x, xhi, xlo, T_TOK*HDIM/4);
  transpose_split<<<dim3(IDIM/32, HDIM/32, NEXP), dim3(32,8), 0, stream>>>(gex, wg_hi, wg_lo, HDIM, IDIM);
  transpose_split<<<dim3(IDIM/32, HDIM/32, NEXP), dim3(32,8), 0, stream>>>(uex, wu_hi, wu_lo, HDIM, IDIM);
  router2_topk<<<T_TOK/4, 256, 0, stream>>>(x, grt, urt, topi_g, topw_g, topi_u, topw_u);
  build_perm<<<NEXP, 256, 0, stream>>>(topi_g, topw_g, offs_g, ptok_g, pw_g);
  build_perm<<<NEXP, 256, 0, stream>>>(topi_u, topw_u, offs_u, ptok_u, pw_u);

  // gate GEMM (last reader of wg region)
  moe_gemm4<<<dim3(IDIM/BN, T_TOK/BM, NEXP), 256, 0, stream>>>(
      xhi, xlo, wg_hi, wg_lo, offs_g, ptok_g, pw_g, gbuf, HDIM, IDIM);

  // wg region dead -> ubuf
  hipMemsetAsync(ubuf, 0, szGI, stream);
  moe_gemm4<<<dim3(IDIM/BN, T_TOK/BM, NEXP), 256, 0, stream>>>(
      xhi, xlo, wu_hi, wu_lo, offs_u, ptok_u, pw_u, ubuf, HDIM, IDIM);

  // wu region dead -> wd_hi
  transpose_split<<<dim3(HDIM/32, IDIM/32, NEXP), dim3(32,8), 0, stream>>>(dex, wd_hi, nullptr, IDIM, HDIM);

  // fused: h = silu(g)*u in-place into gbuf + down-router top2
  swiglu_router<<<T_TOK/4, 256, 0, stream>>>(gbuf, ubuf, drt, topi_d, topw_d);
  build_perm<<<NEXP, 256, 0, stream>>>(topi_d, topw_d, offs_d, ptok_d, pw_d);

  moe_gemm_down<<<dim3(HDIM/BN, T_TOK/BM, NEXP), 256, 0, stream>>>(
      gbuf, wd_hi, offs_d, ptok_d, pw_d, out);
}

// Round 4
// 1910.592 us; speedup vs baseline: 2.3712x; 2.3712x over previous
//
#include <hip/hip_runtime.h>
#include <stdint.h>
#include <stdio.h>

#define T_TOK 8192
#define HDIM  1024
#define IDIM  3584
#define NEXP  8
#define NPAIR (T_TOK*2)
#define BM 128
#define BN 128
#define BK 32

typedef float          f32x4 __attribute__((ext_vector_type(4)));
typedef short          s16x8 __attribute__((ext_vector_type(8)));
typedef unsigned short u16x4 __attribute__((ext_vector_type(4)));
typedef unsigned short u16x8 __attribute__((ext_vector_type(8)));

__device__ __forceinline__ unsigned short f2bf_rne(float f) {
  unsigned u = __float_as_uint(f);
  u += 0x7FFFu + ((u >> 16) & 1u);
  return (unsigned short)(u >> 16);
}
__device__ __forceinline__ float bf2f(unsigned short h) {
  return __uint_as_float(((unsigned)h) << 16);
}

__device__ __forceinline__ void gld16(const void* gsrc, void* ldst) {
  typedef const unsigned int __attribute__((address_space(1))) GU;
  typedef unsigned int       __attribute__((address_space(3))) LU;
  __builtin_amdgcn_global_load_lds((GU*)(unsigned long long)gsrc,
                                   (LU*)(unsigned int)(unsigned long long)ldst,
                                   16, 0, 0);
}

// ================= K1: split f32 -> (hi, lo) bf16 =================
__global__ void split_hilo(const float* __restrict__ in,
                           unsigned short* __restrict__ hi,
                           unsigned short* __restrict__ lo, int n4) {
  int i = blockIdx.x*blockDim.x + threadIdx.x;
  int s = gridDim.x*blockDim.x;
  for (; i < n4; i += s) {
    f32x4 v = ((const f32x4*)in)[i];
    u16x4 h, l;
#pragma unroll
    for (int j = 0; j < 4; j++) {
      float f = v[j];
      unsigned short hb = f2bf_rne(f);
      h[j] = hb;
      l[j] = f2bf_rne(f - bf2f(hb));
    }
    ((u16x4*)hi)[i] = h;
    ((u16x4*)lo)[i] = l;
  }
}

// ===== K2: transpose W [E][K][N] f32 -> Wt [E][N][K] bf16 hi (+lo optional)
__global__ void transpose_split(const float* __restrict__ W,
                                unsigned short* __restrict__ hi,
                                unsigned short* __restrict__ lo,
                                int K, int N) {
  __shared__ float tile[32][33];
  long base = (long)blockIdx.z * K * N;
  int n0 = blockIdx.x*32, k0 = blockIdx.y*32;
  int tx = threadIdx.x, ty = threadIdx.y; // 32 x 8
#pragma unroll
  for (int r = 0; r < 4; r++)
    tile[ty+8*r][tx] = W[base + (long)(k0+ty+8*r)*N + n0 + tx];
  __syncthreads();
#pragma unroll
  for (int r = 0; r < 4; r++) {
    float f = tile[tx][ty+8*r];
    long o = base + (long)(n0+ty+8*r)*K + k0 + tx;
    unsigned short hb = f2bf_rne(f);
    hi[o] = hb;
    if (lo) lo[o] = f2bf_rne(f - bf2f(hb));
  }
}

// ---- shared top-2 helper (stable, lowest-index tie-break like lax.top_k)
__device__ __forceinline__ void top2_write(const float* acc, int t,
                                           int* __restrict__ topi,
                                           float* __restrict__ topw) {
  int i0 = 0; float l0 = acc[0];
#pragma unroll
  for (int e = 1; e < NEXP; e++) if (acc[e] > l0) { l0 = acc[e]; i0 = e; }
  int i1 = -1; float l1 = -3.4e38f;
#pragma unroll
  for (int e = 0; e < NEXP; e++) if (e != i0 && acc[e] > l1) { l1 = acc[e]; i1 = e; }
  float w0 = 1.f/(1.f + expf(l1 - l0));
  float w1 = 1.f/(1.f + expf(l0 - l1));
  topi[2*t]   = i0; topi[2*t+1] = i1;
  topw[2*t]   = w0; topw[2*t+1] = w1;
}

// ===== K3: fused gate+up router (one pass over x) =========================
__global__ __launch_bounds__(256) void router2_topk(
    const float* __restrict__ X,
    const float* __restrict__ RWg, const float* __restrict__ RWu,
    int* __restrict__ tig, float* __restrict__ twg,
    int* __restrict__ tiu, float* __restrict__ twu) {
  int lane = threadIdx.x & 63;
  int t = blockIdx.x*4 + (threadIdx.x>>6);
  const f32x4* xr = (const f32x4*)(X + (long)t*HDIM);
  float ag[NEXP], au[NEXP];
#pragma unroll
  for (int e = 0; e < NEXP; e++) { ag[e] = 0.f; au[e] = 0.f; }
#pragma unroll
  for (int it = 0; it < HDIM/4/64; it++) {   // 4
    int c4 = it*64 + lane;
    f32x4 xv = xr[c4];
#pragma unroll
    for (int j = 0; j < 4; j++) {
      const float* wg = RWg + (long)(c4*4+j)*NEXP;
      const float* wu = RWu + (long)(c4*4+j)*NEXP;
#pragma unroll
      for (int e = 0; e < NEXP; e++) { ag[e] += xv[j]*wg[e]; au[e] += xv[j]*wu[e]; }
    }
  }
#pragma unroll
  for (int e = 0; e < NEXP; e++) {
    float vg = ag[e], vu = au[e];
#pragma unroll
    for (int o = 1; o < 64; o <<= 1) { vg += __shfl_xor(vg, o); vu += __shfl_xor(vu, o); }
    ag[e] = vg; au[e] = vu;
  }
  if (lane == 0) { top2_write(ag, t, tig, twg); top2_write(au, t, tiu, twu); }
}

// ===== K4: deterministic stable per-expert compaction (1 block per expert)
__global__ __launch_bounds__(256) void build_perm(const int* __restrict__ topi,
                                                  const float* __restrict__ topw,
                                                  int* __restrict__ offs,
                                                  int* __restrict__ ptok,
                                                  float* __restrict__ pw) {
  int e = blockIdx.x;
  int tid = threadIdx.x, lane = tid & 63, wv = tid >> 6;
  __shared__ int cnt[NEXP];
  __shared__ int wsum[4];
  if (tid < NEXP) cnt[tid] = 0;
  __syncthreads();
  for (int p = tid; p < NPAIR; p += 256) atomicAdd(&cnt[topi[p]], 1);
  __syncthreads();
  int base = 0;
#pragma unroll
  for (int e2 = 0; e2 < NEXP; e2++) if (e2 < e) base += cnt[e2];
  if (tid == 0) { offs[e] = base; if (e == NEXP-1) offs[NEXP] = base + cnt[e]; }
  for (int p0 = 0; p0 < NPAIR; p0 += 256) {
    int p = p0 + tid;
    bool m = (topi[p] == e);
    unsigned long long b = __ballot(m);
    int lp = __popcll(b & ((1ull << lane) - 1ull));
    if (lane == 0) wsum[wv] = __popcll(b);
    __syncthreads();
    int woff = 0;
#pragma unroll
    for (int w2 = 0; w2 < 4; w2++) if (w2 < wv) woff += wsum[w2];
    int tot = wsum[0] + wsum[1] + wsum[2] + wsum[3];
    if (m) { int dst = base + woff + lp; ptok[dst] = p >> 1; pw[dst] = topw[p]; }
    base += tot;
    __syncthreads();
  }
}

// ===== K5: gathered MoE GEMM, 4-term bf16 split: (Ahi+Alo)@(Bhi+Blo) ======
// Round-2 structure (m97 single-buffer, serial stage): measured 530us/936TF.
__global__ __launch_bounds__(256) void moe_gemm4(
    const unsigned short* __restrict__ Ahi, const unsigned short* __restrict__ Alo,
    const unsigned short* __restrict__ Bhi, const unsigned short* __restrict__ Blo,
    const int* __restrict__ offs, const int* __restrict__ ptok,
    const float* __restrict__ pw, float* __restrict__ out, int K, int N)
{
  const int e = blockIdx.z;
  const int beg = offs[e];
  const int cnt = offs[e+1] - beg;
  const int m0 = blockIdx.y * BM;   // NO swizzle: early-return tails must stay
  if (m0 >= cnt) return;            // spread across XCDs (round-3 lesson)
  const int n0 = blockIdx.x * BN;

  __shared__ unsigned short Ah[BM*BK], Al[BM*BK], Bh[BN*BK], Bl[BN*BK];
  __shared__ int   stok[BM];
  __shared__ float swt[BM];

  const int tid = threadIdx.x, lane = tid & 63, wv = tid >> 6;
  if (tid < BM) {
    int i = m0 + tid;
    stok[tid] = ptok[beg + (i < cnt ? i : 0)];
    swt[tid]  = (i < cnt) ? pw[beg + i] : 0.f;
  }
  __syncthreads();

  const int srow = lane >> 2;
  const int scol = (lane & 3) * 8;
  const int r0 = (wv*2+0)*16 + srow;
  const int r1 = (wv*2+1)*16 + srow;
  const long a0 = (long)stok[r0]*K + scol;
  const long a1 = (long)stok[r1]*K + scol;
  const long b0 = ((long)e*N + n0 + r0)*K + scol;
  const long b1 = ((long)e*N + n0 + r1)*K + scol;
  unsigned short* dA0  = &Ah[(wv*2+0)*16*BK];
  unsigned short* dA1  = &Ah[(wv*2+1)*16*BK];
  unsigned short* dAl0 = &Al[(wv*2+0)*16*BK];
  unsigned short* dAl1 = &Al[(wv*2+1)*16*BK];
  unsigned short* dB0  = &Bh[(wv*2+0)*16*BK];
  unsigned short* dB1  = &Bh[(wv*2+1)*16*BK];
  unsigned short* dBl0 = &Bl[(wv*2+0)*16*BK];
  unsigned short* dBl1 = &Bl[(wv*2+1)*16*BK];

  f32x4 zero = {0.f, 0.f, 0.f, 0.f};
  f32x4 acc[4][4];
#pragma unroll
  for (int i = 0; i < 4; i++)
#pragma unroll
    for (int j = 0; j < 4; j++) acc[i][j] = zero;

  const int arow = (wv>>1)*64, bcol = (wv&1)*64;
  const int fl = lane & 15, fg = lane >> 4;

  for (int kk = 0; kk < K; kk += BK) {
    __syncthreads();
    gld16(Ahi + a0 + kk, dA0);  gld16(Ahi + a1 + kk, dA1);
    gld16(Alo + a0 + kk, dAl0); gld16(Alo + a1 + kk, dAl1);
    gld16(Bhi + b0 + kk, dB0);  gld16(Bhi + b1 + kk, dB1);
    gld16(Blo + b0 + kk, dBl0); gld16(Blo + b1 + kk, dBl1);
    asm volatile("s_waitcnt vmcnt(0)" ::: "memory");
    __syncthreads();

    s16x8 ahf[4], alf[4], bhf[4], blf[4];
#pragma unroll
    for (int i = 0; i < 4; i++) {
      ahf[i] = *(const s16x8*)&Ah[(arow + i*16 + fl)*BK + fg*8];
      alf[i] = *(const s16x8*)&Al[(arow + i*16 + fl)*BK + fg*8];
      bhf[i] = *(const s16x8*)&Bh[(bcol + i*16 + fl)*BK + fg*8];
      blf[i] = *(const s16x8*)&Bl[(bcol + i*16 + fl)*BK + fg*8];
    }
#pragma unroll
    for (int i = 0; i < 4; i++)
#pragma unroll
      for (int j = 0; j < 4; j++) {
        acc[i][j] = __builtin_amdgcn_mfma_f32_16x16x32_bf16(ahf[i], bhf[j], acc[i][j], 0,0,0);
        acc[i][j] = __builtin_amdgcn_mfma_f32_16x16x32_bf16(alf[i], bhf[j], acc[i][j], 0,0,0);
        acc[i][j] = __builtin_amdgcn_mfma_f32_16x16x32_bf16(ahf[i], blf[j], acc[i][j], 0,0,0);
        acc[i][j] = __builtin_amdgcn_mfma_f32_16x16x32_bf16(alf[i], blf[j], acc[i][j], 0,0,0);
      }
  }

  // epilogue: C/D map col=lane&15, row=(lane>>4)*4+r  [m89/m91-verified]
#pragma unroll
  for (int i = 0; i < 4; i++)
#pragma unroll
    for (int r = 0; r < 4; r++) {
      int lrow = arow + i*16 + fg*4 + r;
      if (m0 + lrow < cnt) {
        float wt = swt[lrow];
        long ob = (long)stok[lrow]*N + n0 + bcol + fl;
#pragma unroll
        for (int j = 0; j < 4; j++)
          atomicAdd(&out[ob + j*16], wt * acc[i][j][r]);
      }
    }
}

// ===== K6: fused SwiGLU + down-router (h in-place into g, one pass) =======
__global__ __launch_bounds__(256) void swiglu_router(
    float* __restrict__ g, const float* __restrict__ u,
    const float* __restrict__ RW,           // down router [IDIM][NEXP]
    int* __restrict__ topi, float* __restrict__ topw) {
  int lane = threadIdx.x & 63;
  int t = blockIdx.x*4 + (threadIdx.x>>6);
  f32x4*       gr = (f32x4*)(g + (long)t*IDIM);
  const f32x4* ur = (const f32x4*)(u + (long)t*IDIM);
  float acc[NEXP];
#pragma unroll
  for (int e = 0; e < NEXP; e++) acc[e] = 0.f;
#pragma unroll
  for (int it = 0; it < IDIM/4/64; it++) {   // 14
    int c4 = it*64 + lane;
    f32x4 gv = gr[c4], uv = ur[c4], hv;
#pragma unroll
    for (int j = 0; j < 4; j++) {
      float x = gv[j];
      hv[j] = x * uv[j] / (1.f + expf(-x));
    }
    gr[c4] = hv;
#pragma unroll
    for (int j = 0; j < 4; j++) {
      const float* wr = RW + (long)(c4*4+j)*NEXP;
#pragma unroll
      for (int e = 0; e < NEXP; e++) acc[e] += hv[j]*wr[e];
    }
  }
#pragma unroll
  for (int e = 0; e < NEXP; e++) {
    float v = acc[e];
#pragma unroll
    for (int o = 1; o < 64; o <<= 1) v += __shfl_xor(v, o);
    acc[e] = v;
  }
  if (lane == 0) top2_write(acc, t, topi, topw);
}

// ===== K7: down GEMM: A = h f32 (split in-kernel), B = Wd_hi bf16 =========
// Round-2 structure (single-buffer).
__global__ __launch_bounds__(256) void moe_gemm_down(
    const float* __restrict__ Hf, const unsigned short* __restrict__ Bw,
    const int* __restrict__ offs, const int* __restrict__ ptok,
    const float* __restrict__ pw, float* __restrict__ out)
{
  const int K = IDIM, N = HDIM;
  const int e = blockIdx.z;
  const int beg = offs[e];
  const int cnt = offs[e+1] - beg;
  const int m0 = blockIdx.y * BM;   // NO swizzle
  if (m0 >= cnt) return;
  const int n0 = blockIdx.x * BN;

  __shared__ unsigned short Ah[BM*BK], Al[BM*BK], Bh[BN*BK];
  __shared__ int   stok[BM];
  __shared__ float swt[BM];

  const int tid = threadIdx.x, lane = tid & 63, wv = tid >> 6;
  if (tid < BM) {
    int i = m0 + tid;
    stok[tid] = ptok[beg + (i < cnt ? i : 0)];
    swt[tid]  = (i < cnt) ? pw[beg + i] : 0.f;
  }
  __syncthreads();

  const int arw = tid >> 1, half = tid & 1;
  const float* asrc = Hf + (long)stok[arw]*K + half*16;
  unsigned short* awh = &Ah[arw*BK + half*16];
  unsigned short* awl = &Al[arw*BK + half*16];

  const int srow = lane >> 2, scol = (lane & 3)*8;
  const int r0 = (wv*2+0)*16 + srow, r1 = (wv*2+1)*16 + srow;
  const long b0 = ((long)e*N + n0 + r0)*K + scol;
  const long b1 = ((long)e*N + n0 + r1)*K + scol;
  unsigned short* dB0 = &Bh[(wv*2+0)*16*BK];
  unsigned short* dB1 = &Bh[(wv*2+1)*16*BK];

  f32x4 zero = {0.f,0.f,0.f,0.f};
  f32x4 acc[4][4];
#pragma unroll
  for (int i = 0; i < 4; i++)
#pragma unroll
    for (int j = 0; j < 4; j++) acc[i][j] = zero;

  const int arow = (wv>>1)*64, bcol = (wv&1)*64;
  const int fl = lane & 15, fg = lane >> 4;

  for (int kk = 0; kk < K; kk += BK) {
    f32x4 v0 = ((const f32x4*)(asrc + kk))[0];
    f32x4 v1 = ((const f32x4*)(asrc + kk))[1];
    f32x4 v2 = ((const f32x4*)(asrc + kk))[2];
    f32x4 v3 = ((const f32x4*)(asrc + kk))[3];
    u16x8 ha, la, hb2, lb2;
#define SP1(F,HV,LV,IX) { float _f=(F); unsigned short _h=f2bf_rne(_f); HV[IX]=_h; LV[IX]=f2bf_rne(_f - bf2f(_h)); }
    SP1(v0[0],ha,la,0) SP1(v0[1],ha,la,1) SP1(v0[2],ha,la,2) SP1(v0[3],ha,la,3)
    SP1(v1[0],ha,la,4) SP1(v1[1],ha,la,5) SP1(v1[2],ha,la,6) SP1(v1[3],ha,la,7)
    SP1(v2[0],hb2,lb2,0) SP1(v2[1],hb2,lb2,1) SP1(v2[2],hb2,lb2,2) SP1(v2[3],hb2,lb2,3)
    SP1(v3[0],hb2,lb2,4) SP1(v3[1],hb2,lb2,5) SP1(v3[2],hb2,lb2,6) SP1(v3[3],hb2,lb2,7)
#undef SP1
    __syncthreads();
    gld16(Bw + b0 + kk, dB0);
    gld16(Bw + b1 + kk, dB1);
    *(u16x8*)awh = ha;       *(u16x8*)(awh+8) = hb2;
    *(u16x8*)awl = la;       *(u16x8*)(awl+8) = lb2;
    asm volatile("s_waitcnt vmcnt(0)" ::: "memory");
    __syncthreads();

    s16x8 ahf[4], alf[4], bhf[4];
#pragma unroll
    for (int i = 0; i < 4; i++) {
      ahf[i] = *(const s16x8*)&Ah[(arow + i*16 + fl)*BK + fg*8];
      alf[i] = *(const s16x8*)&Al[(arow + i*16 + fl)*BK + fg*8];
      bhf[i] = *(const s16x8*)&Bh[(bcol + i*16 + fl)*BK + fg*8];
    }
#pragma unroll
    for (int i = 0; i < 4; i++)
#pragma unroll
      for (int j = 0; j < 4; j++) {
        acc[i][j] = __builtin_amdgcn_mfma_f32_16x16x32_bf16(ahf[i], bhf[j], acc[i][j], 0,0,0);
        acc[i][j] = __builtin_amdgcn_mfma_f32_16x16x32_bf16(alf[i], bhf[j], acc[i][j], 0,0,0);
      }
  }

#pragma unroll
  for (int i = 0; i < 4; i++)
#pragma unroll
    for (int r = 0; r < 4; r++) {
      int lrow = arow + i*16 + fg*4 + r;
      if (m0 + lrow < cnt) {
        float wt = swt[lrow];
        long ob = (long)stok[lrow]*N + n0 + bcol + fl;
#pragma unroll
        for (int j = 0; j < 4; j++)
          atomicAdd(&out[ob + j*16], wt * acc[i][j][r]);
      }
    }
}

// ========================== host launcher =================================
// Workspace aliasing (448 MiB avail, peak ~387 MB):
//   ubuf  aliases [wg_hi, wg_lo] — first written AFTER gate GEMM (last wg reader)
//   wd_hi aliases [wu_hi, ...]   — transposed AFTER up GEMM (last wu reader)
extern "C" void kernel_launch(void* const* d_in, const int* in_sizes, int n_in,
                              void* d_out, int out_size, void* d_ws, size_t ws_size,
                              hipStream_t stream)
{
  (void)in_sizes; (void)n_in;
  const float* x   = (const float*)d_in[0];
  const float* grt = (const float*)d_in[1];
  const float* gex = (const float*)d_in[2];
  const float* urt = (const float*)d_in[3];
  const float* uex = (const float*)d_in[4];
  const float* drt = (const float*)d_in[5];
  const float* dex = (const float*)d_in[6];
  float* out = (float*)d_out;

  char* base = (char*)d_ws;
  size_t off = 0;
  auto alloc = [&](size_t b) -> void* {
    void* r = base + off;
    off = (off + b + 255) & ~(size_t)255;
    return r;
  };
  const size_t szXH = (size_t)T_TOK*HDIM*2;
  const size_t szW  = (size_t)NEXP*HDIM*IDIM*2;
  const size_t szGI = (size_t)T_TOK*IDIM*4;

  unsigned short* xhi   = (unsigned short*)alloc(szXH);
  unsigned short* xlo   = (unsigned short*)alloc(szXH);
  unsigned short* wg_hi = (unsigned short*)alloc(szW);   // later: ubuf (f32)
  unsigned short* wg_lo = (unsigned short*)alloc(szW);
  unsigned short* wu_hi = (unsigned short*)alloc(szW);   // later: wd_hi
  unsigned short* wu_lo = (unsigned short*)alloc(szW);
  float* gbuf = (float*)alloc(szGI);
  int*   topi_g = (int*)alloc(NPAIR*4);  float* topw_g = (float*)alloc(NPAIR*4);
  int*   topi_u = (int*)alloc(NPAIR*4);  float* topw_u = (float*)alloc(NPAIR*4);
  int*   topi_d = (int*)alloc(NPAIR*4);  float* topw_d = (float*)alloc(NPAIR*4);
  int* offs_g = (int*)alloc(64);
  int* offs_u = (int*)alloc(64);
  int* offs_d = (int*)alloc(64);
  int*   ptok_g = (int*)alloc(NPAIR*4);  float* pw_g = (float*)alloc(NPAIR*4);
  int*   ptok_u = (int*)alloc(NPAIR*4);  float* pw_u = (float*)alloc(NPAIR*4);
  int*   ptok_d = (int*)alloc(NPAIR*4);  float* pw_d = (float*)alloc(NPAIR*4);

  float*          ubuf  = (float*)wg_hi;
  unsigned short* wd_hi = wu_hi;

  if (off > ws_size) {
    fprintf(stderr, "[moe] ws too small: need %zu bytes, have %zu\n", off, ws_size);
    hipMemsetAsync(d_out, 0, (size_t)out_size*sizeof(float), stream);
    return;
  }

  hipMemsetAsync(gbuf, 0, szGI, stream);
  hipMemsetAsync(d_out, 0, (size_t)out_size*sizeof(float), stream);

  split_hilo<<<2048, 256, 0, stream>>>(x, xhi, xlo, T_TOK*HDIM/4);
  transpose_split<<<dim3(IDIM/32, HDIM/32, NEXP), dim3(32,8), 0, stream>>>(gex, wg_hi, wg_lo, HDIM, IDIM);
  transpose_split<<<dim3(IDIM/32, HDIM/32, NEXP), dim3(32,8), 0, stream>>>(uex, wu_hi, wu_lo, HDIM, IDIM);
  router2_topk<<<T_TOK/4, 256, 0, stream>>>(x, grt, urt, topi_g, topw_g, topi_u, topw_u);
  build_perm<<<NEXP, 256, 0, stream>>>(topi_g, topw_g, offs_g, ptok_g, pw_g);
  build_perm<<<NEXP, 256, 0, stream>>>(topi_u, topw_u, offs_u, ptok_u, pw_u);

  // gate GEMM (last reader of wg region)
  moe_gemm4<<<dim3(IDIM/BN, T_TOK/BM, NEXP), 256, 0, stream>>>(
      xhi, xlo, wg_hi, wg_lo, offs_g, ptok_g, pw_g, gbuf, HDIM, IDIM);

  // wg region dead -> ubuf
  hipMemsetAsync(ubuf, 0, szGI, stream);
  moe_gemm4<<<dim3(IDIM/BN, T_TOK/BM, NEXP), 256, 0, stream>>>(
      xhi, xlo, wu_hi, wu_lo, offs_u, ptok_u, pw_u, ubuf, HDIM, IDIM);

  // wu region dead -> wd_hi
  transpose_split<<<dim3(HDIM/32, IDIM/32, NEXP), dim3(32,8), 0, stream>>>(dex, wd_hi, nullptr, IDIM, HDIM);

  // fused: h = silu(g)*u in-place into gbuf + down-router top2
  swiglu_router<<<T_TOK/4, 256, 0, stream>>>(gbuf, ubuf, drt, topi_d, topw_d);
  build_perm<<<NEXP, 256, 0, stream>>>(topi_d, topw_d, offs_d, ptok_d, pw_d);

  moe_gemm_down<<<dim3(HDIM/BN, T_TOK/BM, NEXP), 256, 0, stream>>>(
      gbuf, wd_hi, offs_d, ptok_d, pw_d, out);
}

// Round 5
// 1781.937 us; speedup vs baseline: 2.5424x; 1.0722x over previous
//
#include <hip/hip_runtime.h>
#include <stdint.h>
#include <stdio.h>

#define T_TOK 8192
#define HDIM  1024
#define IDIM  3584
#define NEXP  8
#define NPAIR (T_TOK*2)
#define BM 128
#define BN 128
#define BK 32

typedef float          f32x4 __attribute__((ext_vector_type(4)));
typedef short          s16x8 __attribute__((ext_vector_type(8)));
typedef unsigned short u16x4 __attribute__((ext_vector_type(4)));
typedef unsigned short u16x8 __attribute__((ext_vector_type(8)));

__device__ __forceinline__ unsigned short f2bf_rne(float f) {
  unsigned u = __float_as_uint(f);
  u += 0x7FFFu + ((u >> 16) & 1u);
  return (unsigned short)(u >> 16);
}
__device__ __forceinline__ float bf2f(unsigned short h) {
  return __uint_as_float(((unsigned)h) << 16);
}

__device__ __forceinline__ void gld16(const void* gsrc, void* ldst) {
  typedef const unsigned int __attribute__((address_space(1))) GU;
  typedef unsigned int       __attribute__((address_space(3))) LU;
  __builtin_amdgcn_global_load_lds((GU*)(unsigned long long)gsrc,
                                   (LU*)(unsigned int)(unsigned long long)ldst,
                                   16, 0, 0);
}

// ================= K1: split f32 -> (hi, lo) bf16 =================
__global__ void split_hilo(const float* __restrict__ in,
                           unsigned short* __restrict__ hi,
                           unsigned short* __restrict__ lo, int n4) {
  int i = blockIdx.x*blockDim.x + threadIdx.x;
  int s = gridDim.x*blockDim.x;
  for (; i < n4; i += s) {
    f32x4 v = ((const f32x4*)in)[i];
    u16x4 h, l;
#pragma unroll
    for (int j = 0; j < 4; j++) {
      float f = v[j];
      unsigned short hb = f2bf_rne(f);
      h[j] = hb;
      l[j] = f2bf_rne(f - bf2f(hb));
    }
    ((u16x4*)hi)[i] = h;
    ((u16x4*)lo)[i] = l;
  }
}

// ===== K2: transpose W [E][K][N] f32 -> Wt [E][N][K] bf16 hi (+lo optional)
__global__ void transpose_split(const float* __restrict__ W,
                                unsigned short* __restrict__ hi,
                                unsigned short* __restrict__ lo,
                                int K, int N) {
  __shared__ float tile[32][33];
  long base = (long)blockIdx.z * K * N;
  int n0 = blockIdx.x*32, k0 = blockIdx.y*32;
  int tx = threadIdx.x, ty = threadIdx.y; // 32 x 8
#pragma unroll
  for (int r = 0; r < 4; r++)
    tile[ty+8*r][tx] = W[base + (long)(k0+ty+8*r)*N + n0 + tx];
  __syncthreads();
#pragma unroll
  for (int r = 0; r < 4; r++) {
    float f = tile[tx][ty+8*r];
    long o = base + (long)(n0+ty+8*r)*K + k0 + tx;
    unsigned short hb = f2bf_rne(f);
    hi[o] = hb;
    if (lo) lo[o] = f2bf_rne(f - bf2f(hb));
  }
}

// ---- shared top-2 helper (stable, lowest-index tie-break like lax.top_k)
__device__ __forceinline__ void top2_write(const float* acc, int t,
                                           int* __restrict__ topi,
                                           float* __restrict__ topw) {
  int i0 = 0; float l0 = acc[0];
#pragma unroll
  for (int e = 1; e < NEXP; e++) if (acc[e] > l0) { l0 = acc[e]; i0 = e; }
  int i1 = -1; float l1 = -3.4e38f;
#pragma unroll
  for (int e = 0; e < NEXP; e++) if (e != i0 && acc[e] > l1) { l1 = acc[e]; i1 = e; }
  float w0 = 1.f/(1.f + expf(l1 - l0));
  float w1 = 1.f/(1.f + expf(l0 - l1));
  topi[2*t]   = i0; topi[2*t+1] = i1;
  topw[2*t]   = w0; topw[2*t+1] = w1;
}

// ===== K3: fused gate+up router (one pass over x) =========================
__global__ __launch_bounds__(256) void router2_topk(
    const float* __restrict__ X,
    const float* __restrict__ RWg, const float* __restrict__ RWu,
    int* __restrict__ tig, float* __restrict__ twg,
    int* __restrict__ tiu, float* __restrict__ twu) {
  int lane = threadIdx.x & 63;
  int t = blockIdx.x*4 + (threadIdx.x>>6);
  const f32x4* xr = (const f32x4*)(X + (long)t*HDIM);
  float ag[NEXP], au[NEXP];
#pragma unroll
  for (int e = 0; e < NEXP; e++) { ag[e] = 0.f; au[e] = 0.f; }
#pragma unroll
  for (int it = 0; it < HDIM/4/64; it++) {   // 4
    int c4 = it*64 + lane;
    f32x4 xv = xr[c4];
#pragma unroll
    for (int j = 0; j < 4; j++) {
      const float* wg = RWg + (long)(c4*4+j)*NEXP;
      const float* wu = RWu + (long)(c4*4+j)*NEXP;
#pragma unroll
      for (int e = 0; e < NEXP; e++) { ag[e] += xv[j]*wg[e]; au[e] += xv[j]*wu[e]; }
    }
  }
#pragma unroll
  for (int e = 0; e < NEXP; e++) {
    float vg = ag[e], vu = au[e];
#pragma unroll
    for (int o = 1; o < 64; o <<= 1) { vg += __shfl_xor(vg, o); vu += __shfl_xor(vu, o); }
    ag[e] = vg; au[e] = vu;
  }
  if (lane == 0) { top2_write(ag, t, tig, twg); top2_write(au, t, tiu, twu); }
}

// ===== K4: deterministic stable per-expert compaction (1 block per expert)
__global__ __launch_bounds__(256) void build_perm(const int* __restrict__ topi,
                                                  const float* __restrict__ topw,
                                                  int* __restrict__ offs,
                                                  int* __restrict__ ptok,
                                                  float* __restrict__ pw) {
  int e = blockIdx.x;
  int tid = threadIdx.x, lane = tid & 63, wv = tid >> 6;
  __shared__ int cnt[NEXP];
  __shared__ int wsum[4];
  if (tid < NEXP) cnt[tid] = 0;
  __syncthreads();
  for (int p = tid; p < NPAIR; p += 256) atomicAdd(&cnt[topi[p]], 1);
  __syncthreads();
  int base = 0;
#pragma unroll
  for (int e2 = 0; e2 < NEXP; e2++) if (e2 < e) base += cnt[e2];
  if (tid == 0) { offs[e] = base; if (e == NEXP-1) offs[NEXP] = base + cnt[e]; }
  for (int p0 = 0; p0 < NPAIR; p0 += 256) {
    int p = p0 + tid;
    bool m = (topi[p] == e);
    unsigned long long b = __ballot(m);
    int lp = __popcll(b & ((1ull << lane) - 1ull));
    if (lane == 0) wsum[wv] = __popcll(b);
    __syncthreads();
    int woff = 0;
#pragma unroll
    for (int w2 = 0; w2 < 4; w2++) if (w2 < wv) woff += wsum[w2];
    int tot = wsum[0] + wsum[1] + wsum[2] + wsum[3];
    if (m) { int dst = base + woff + lp; ptok[dst] = p >> 1; pw[dst] = topw[p]; }
    base += tot;
    __syncthreads();
  }
}

// ===== K5: gathered MoE GEMM, 3-term bf16 split ===========================
// (Ahi+Alo)@(Bhi+Blo) minus the lo@lo term (~2^-18 relative — negligible).
// m97 single-buffer structure (known 530us @ 4-term); staging unchanged.
__global__ __launch_bounds__(256) void moe_gemm3(
    const unsigned short* __restrict__ Ahi, const unsigned short* __restrict__ Alo,
    const unsigned short* __restrict__ Bhi, const unsigned short* __restrict__ Blo,
    const int* __restrict__ offs, const int* __restrict__ ptok,
    const float* __restrict__ pw, float* __restrict__ out, int K, int N)
{
  const int e = blockIdx.z;
  const int beg = offs[e];
  const int cnt = offs[e+1] - beg;
  const int m0 = blockIdx.y * BM;   // NO swizzle (round-3 lesson: early-return
  if (m0 >= cnt) return;            // tails must stay spread across XCDs)
  const int n0 = blockIdx.x * BN;

  __shared__ unsigned short Ah[BM*BK], Al[BM*BK], Bh[BN*BK], Bl[BN*BK];
  __shared__ int   stok[BM];
  __shared__ float swt[BM];

  const int tid = threadIdx.x, lane = tid & 63, wv = tid >> 6;
  if (tid < BM) {
    int i = m0 + tid;
    stok[tid] = ptok[beg + (i < cnt ? i : 0)];
    swt[tid]  = (i < cnt) ? pw[beg + i] : 0.f;
  }
  __syncthreads();

  const int srow = lane >> 2;
  const int scol = (lane & 3) * 8;
  const int r0 = (wv*2+0)*16 + srow;
  const int r1 = (wv*2+1)*16 + srow;
  const long a0 = (long)stok[r0]*K + scol;
  const long a1 = (long)stok[r1]*K + scol;
  const long b0 = ((long)e*N + n0 + r0)*K + scol;
  const long b1 = ((long)e*N + n0 + r1)*K + scol;
  unsigned short* dA0  = &Ah[(wv*2+0)*16*BK];
  unsigned short* dA1  = &Ah[(wv*2+1)*16*BK];
  unsigned short* dAl0 = &Al[(wv*2+0)*16*BK];
  unsigned short* dAl1 = &Al[(wv*2+1)*16*BK];
  unsigned short* dB0  = &Bh[(wv*2+0)*16*BK];
  unsigned short* dB1  = &Bh[(wv*2+1)*16*BK];
  unsigned short* dBl0 = &Bl[(wv*2+0)*16*BK];
  unsigned short* dBl1 = &Bl[(wv*2+1)*16*BK];

  f32x4 zero = {0.f, 0.f, 0.f, 0.f};
  f32x4 acc[4][4];
#pragma unroll
  for (int i = 0; i < 4; i++)
#pragma unroll
    for (int j = 0; j < 4; j++) acc[i][j] = zero;

  const int arow = (wv>>1)*64, bcol = (wv&1)*64;
  const int fl = lane & 15, fg = lane >> 4;

  for (int kk = 0; kk < K; kk += BK) {
    __syncthreads();
    gld16(Ahi + a0 + kk, dA0);  gld16(Ahi + a1 + kk, dA1);
    gld16(Alo + a0 + kk, dAl0); gld16(Alo + a1 + kk, dAl1);
    gld16(Bhi + b0 + kk, dB0);  gld16(Bhi + b1 + kk, dB1);
    gld16(Blo + b0 + kk, dBl0); gld16(Blo + b1 + kk, dBl1);
    asm volatile("s_waitcnt vmcnt(0)" ::: "memory");
    __syncthreads();

    s16x8 ahf[4], alf[4], bhf[4], blf[4];
#pragma unroll
    for (int i = 0; i < 4; i++) {
      ahf[i] = *(const s16x8*)&Ah[(arow + i*16 + fl)*BK + fg*8];
      alf[i] = *(const s16x8*)&Al[(arow + i*16 + fl)*BK + fg*8];
      bhf[i] = *(const s16x8*)&Bh[(bcol + i*16 + fl)*BK + fg*8];
      blf[i] = *(const s16x8*)&Bl[(bcol + i*16 + fl)*BK + fg*8];
    }
#pragma unroll
    for (int i = 0; i < 4; i++)
#pragma unroll
      for (int j = 0; j < 4; j++) {
        acc[i][j] = __builtin_amdgcn_mfma_f32_16x16x32_bf16(ahf[i], bhf[j], acc[i][j], 0,0,0);
        acc[i][j] = __builtin_amdgcn_mfma_f32_16x16x32_bf16(alf[i], bhf[j], acc[i][j], 0,0,0);
        acc[i][j] = __builtin_amdgcn_mfma_f32_16x16x32_bf16(ahf[i], blf[j], acc[i][j], 0,0,0);
        // lo@lo term dropped (round-5): ~2^-18 relative on h
      }
  }

  // epilogue: C/D map col=lane&15, row=(lane>>4)*4+r  [m89/m91-verified]
#pragma unroll
  for (int i = 0; i < 4; i++)
#pragma unroll
    for (int r = 0; r < 4; r++) {
      int lrow = arow + i*16 + fg*4 + r;
      if (m0 + lrow < cnt) {
        float wt = swt[lrow];
        long ob = (long)stok[lrow]*N + n0 + bcol + fl;
#pragma unroll
        for (int j = 0; j < 4; j++)
          atomicAdd(&out[ob + j*16], wt * acc[i][j][r]);
      }
    }
}

// ===== K6: fused SwiGLU + down-router (h in-place into g, one pass) =======
__global__ __launch_bounds__(256) void swiglu_router(
    float* __restrict__ g, const float* __restrict__ u,
    const float* __restrict__ RW,           // down router [IDIM][NEXP]
    int* __restrict__ topi, float* __restrict__ topw) {
  int lane = threadIdx.x & 63;
  int t = blockIdx.x*4 + (threadIdx.x>>6);
  f32x4*       gr = (f32x4*)(g + (long)t*IDIM);
  const f32x4* ur = (const f32x4*)(u + (long)t*IDIM);
  float acc[NEXP];
#pragma unroll
  for (int e = 0; e < NEXP; e++) acc[e] = 0.f;
#pragma unroll
  for (int it = 0; it < IDIM/4/64; it++) {   // 14
    int c4 = it*64 + lane;
    f32x4 gv = gr[c4], uv = ur[c4], hv;
#pragma unroll
    for (int j = 0; j < 4; j++) {
      float x = gv[j];
      hv[j] = x * uv[j] / (1.f + expf(-x));
    }
    gr[c4] = hv;
#pragma unroll
    for (int j = 0; j < 4; j++) {
      const float* wr = RW + (long)(c4*4+j)*NEXP;
#pragma unroll
      for (int e = 0; e < NEXP; e++) acc[e] += hv[j]*wr[e];
    }
  }
#pragma unroll
  for (int e = 0; e < NEXP; e++) {
    float v = acc[e];
#pragma unroll
    for (int o = 1; o < 64; o <<= 1) v += __shfl_xor(v, o);
    acc[e] = v;
  }
  if (lane == 0) top2_write(acc, t, topi, topw);
}

// ===== K7: down GEMM, 1-term: A = bf16(h), B = Wd_hi bf16 =================
// Routing already decided on exact h; dropping h_lo only perturbs VALUES
// (~1e-2 worst-case vs 3.2e-2 threshold). T14: next A-tile's f32 loads are
// issued right after the barrier so HBM latency hides under MFMA.
__global__ __launch_bounds__(256) void moe_gemm_down(
    const float* __restrict__ Hf, const unsigned short* __restrict__ Bw,
    const int* __restrict__ offs, const int* __restrict__ ptok,
    const float* __restrict__ pw, float* __restrict__ out)
{
  const int K = IDIM, N = HDIM;
  const int e = blockIdx.z;
  const int beg = offs[e];
  const int cnt = offs[e+1] - beg;
  const int m0 = blockIdx.y * BM;   // NO swizzle
  if (m0 >= cnt) return;
  const int n0 = blockIdx.x * BN;

  __shared__ unsigned short Ah[BM*BK], Bh[BN*BK];
  __shared__ int   stok[BM];
  __shared__ float swt[BM];

  const int tid = threadIdx.x, lane = tid & 63, wv = tid >> 6;
  if (tid < BM) {
    int i = m0 + tid;
    stok[tid] = ptok[beg + (i < cnt ? i : 0)];
    swt[tid]  = (i < cnt) ? pw[beg + i] : 0.f;
  }
  __syncthreads();

  // A path: each thread owns half a row (16 f32 -> 16 bf16)
  const int arw = tid >> 1, half = tid & 1;
  const float* asrc = Hf + (long)stok[arw]*K + half*16;
  const int awoff = arw*BK + half*16;

  // B path: gld16 staging
  const int srow = lane >> 2, scol = (lane & 3)*8;
  const int r0 = (wv*2+0)*16 + srow, r1 = (wv*2+1)*16 + srow;
  const long b0 = ((long)e*N + n0 + r0)*K + scol;
  const long b1 = ((long)e*N + n0 + r1)*K + scol;
  unsigned short* dB0 = &Bh[(wv*2+0)*16*BK];
  unsigned short* dB1 = &Bh[(wv*2+1)*16*BK];

  f32x4 zero = {0.f,0.f,0.f,0.f};
  f32x4 acc[4][4];
#pragma unroll
  for (int i = 0; i < 4; i++)
#pragma unroll
    for (int j = 0; j < 4; j++) acc[i][j] = zero;

  const int arow = (wv>>1)*64, bcol = (wv&1)*64;
  const int fl = lane & 15, fg = lane >> 4;

  f32x4 p0, p1, p2, p3;
#define LOADA(kk) do {                        \
    p0 = ((const f32x4*)(asrc + (kk)))[0];    \
    p1 = ((const f32x4*)(asrc + (kk)))[1];    \
    p2 = ((const f32x4*)(asrc + (kk)))[2];    \
    p3 = ((const f32x4*)(asrc + (kk)))[3];    \
  } while (0)

  LOADA(0);  // prologue: A regs for tile 0

  for (int kk = 0; kk < K; kk += BK) {
    __syncthreads();                 // everyone done reading LDS (prev step)
    gld16(Bw + b0 + kk, dB0);
    gld16(Bw + b1 + kk, dB1);
    // cvt regs -> bf16, write A tile (data loaded during prev step's MFMA)
    u16x8 ha, hb2;
    ha[0]=f2bf_rne(p0[0]); ha[1]=f2bf_rne(p0[1]); ha[2]=f2bf_rne(p0[2]); ha[3]=f2bf_rne(p0[3]);
    ha[4]=f2bf_rne(p1[0]); ha[5]=f2bf_rne(p1[1]); ha[6]=f2bf_rne(p1[2]); ha[7]=f2bf_rne(p1[3]);
    hb2[0]=f2bf_rne(p2[0]); hb2[1]=f2bf_rne(p2[1]); hb2[2]=f2bf_rne(p2[2]); hb2[3]=f2bf_rne(p2[3]);
    hb2[4]=f2bf_rne(p3[0]); hb2[5]=f2bf_rne(p3[1]); hb2[6]=f2bf_rne(p3[2]); hb2[7]=f2bf_rne(p3[3]);
    *(u16x8*)&Ah[awoff]   = ha;
    *(u16x8*)&Ah[awoff+8] = hb2;
    asm volatile("s_waitcnt vmcnt(0)" ::: "memory");
    __syncthreads();                 // B landed + A written

    if (kk + BK < K) LOADA(kk + BK); // T14: issue next A loads under MFMA

    s16x8 ahf[4], bhf[4];
#pragma unroll
    for (int i = 0; i < 4; i++) {
      ahf[i] = *(const s16x8*)&Ah[(arow + i*16 + fl)*BK + fg*8];
      bhf[i] = *(const s16x8*)&Bh[(bcol + i*16 + fl)*BK + fg*8];
    }
#pragma unroll
    for (int i = 0; i < 4; i++)
#pragma unroll
      for (int j = 0; j < 4; j++)
        acc[i][j] = __builtin_amdgcn_mfma_f32_16x16x32_bf16(ahf[i], bhf[j], acc[i][j], 0,0,0);
  }
#undef LOADA

#pragma unroll
  for (int i = 0; i < 4; i++)
#pragma unroll
    for (int r = 0; r < 4; r++) {
      int lrow = arow + i*16 + fg*4 + r;
      if (m0 + lrow < cnt) {
        float wt = swt[lrow];
        long ob = (long)stok[lrow]*N + n0 + bcol + fl;
#pragma unroll
        for (int j = 0; j < 4; j++)
          atomicAdd(&out[ob + j*16], wt * acc[i][j][r]);
      }
    }
}

// ========================== host launcher =================================
// Workspace aliasing (448 MiB avail, peak ~387 MB):
//   ubuf  aliases [wg_hi, wg_lo] — first written AFTER gate GEMM (last wg reader)
//   wd_hi aliases [wu_hi, ...]   — transposed AFTER up GEMM (last wu reader)
extern "C" void kernel_launch(void* const* d_in, const int* in_sizes, int n_in,
                              void* d_out, int out_size, void* d_ws, size_t ws_size,
                              hipStream_t stream)
{
  (void)in_sizes; (void)n_in;
  const float* x   = (const float*)d_in[0];
  const float* grt = (const float*)d_in[1];
  const float* gex = (const float*)d_in[2];
  const float* urt = (const float*)d_in[3];
  const float* uex = (const float*)d_in[4];
  const float* drt = (const float*)d_in[5];
  const float* dex = (const float*)d_in[6];
  float* out = (float*)d_out;

  char* base = (char*)d_ws;
  size_t off = 0;
  auto alloc = [&](size_t b) -> void* {
    void* r = base + off;
    off = (off + b + 255) & ~(size_t)255;
    return r;
  };
  const size_t szXH = (size_t)T_TOK*HDIM*2;
  const size_t szW  = (size_t)NEXP*HDIM*IDIM*2;
  const size_t szGI = (size_t)T_TOK*IDIM*4;

  unsigned short* xhi   = (unsigned short*)alloc(szXH);
  unsigned short* xlo   = (unsigned short*)alloc(szXH);
  unsigned short* wg_hi = (unsigned short*)alloc(szW);   // later: ubuf (f32)
  unsigned short* wg_lo = (unsigned short*)alloc(szW);
  unsigned short* wu_hi = (unsigned short*)alloc(szW);   // later: wd_hi
  unsigned short* wu_lo = (unsigned short*)alloc(szW);
  float* gbuf = (float*)alloc(szGI);
  int*   topi_g = (int*)alloc(NPAIR*4);  float* topw_g = (float*)alloc(NPAIR*4);
  int*   topi_u = (int*)alloc(NPAIR*4);  float* topw_u = (float*)alloc(NPAIR*4);
  int*   topi_d = (int*)alloc(NPAIR*4);  float* topw_d = (float*)alloc(NPAIR*4);
  int* offs_g = (int*)alloc(64);
  int* offs_u = (int*)alloc(64);
  int* offs_d = (int*)alloc(64);
  int*   ptok_g = (int*)alloc(NPAIR*4);  float* pw_g = (float*)alloc(NPAIR*4);
  int*   ptok_u = (int*)alloc(NPAIR*4);  float* pw_u = (float*)alloc(NPAIR*4);
  int*   ptok_d = (int*)alloc(NPAIR*4);  float* pw_d = (float*)alloc(NPAIR*4);

  float*          ubuf  = (float*)wg_hi;
  unsigned short* wd_hi = wu_hi;

  if (off > ws_size) {
    fprintf(stderr, "[moe] ws too small: need %zu bytes, have %zu\n", off, ws_size);
    hipMemsetAsync(d_out, 0, (size_t)out_size*sizeof(float), stream);
    return;
  }

  hipMemsetAsync(gbuf, 0, szGI, stream);
  hipMemsetAsync(d_out, 0, (size_t)out_size*sizeof(float), stream);

  split_hilo<<<2048, 256, 0, stream>>>(x, xhi, xlo, T_TOK*HDIM/4);
  transpose_split<<<dim3(IDIM/32, HDIM/32, NEXP), dim3(32,8), 0, stream>>>(gex, wg_hi, wg_lo, HDIM, IDIM);
  transpose_split<<<dim3(IDIM/32, HDIM/32, NEXP), dim3(32,8), 0, stream>>>(uex, wu_hi, wu_lo, HDIM, IDIM);
  router2_topk<<<T_TOK/4, 256, 0, stream>>>(x, grt, urt, topi_g, topw_g, topi_u, topw_u);
  build_perm<<<NEXP, 256, 0, stream>>>(topi_g, topw_g, offs_g, ptok_g, pw_g);
  build_perm<<<NEXP, 256, 0, stream>>>(topi_u, topw_u, offs_u, ptok_u, pw_u);

  // gate GEMM (last reader of wg region)
  moe_gemm3<<<dim3(IDIM/BN, T_TOK/BM, NEXP), 256, 0, stream>>>(
      xhi, xlo, wg_hi, wg_lo, offs_g, ptok_g, pw_g, gbuf, HDIM, IDIM);

  // wg region dead -> ubuf
  hipMemsetAsync(ubuf, 0, szGI, stream);
  moe_gemm3<<<dim3(IDIM/BN, T_TOK/BM, NEXP), 256, 0, stream>>>(
      xhi, xlo, wu_hi, wu_lo, offs_u, ptok_u, pw_u, ubuf, HDIM, IDIM);

  // wu region dead -> wd_hi
  transpose_split<<<dim3(HDIM/32, IDIM/32, NEXP), dim3(32,8), 0, stream>>>(dex, wd_hi, nullptr, IDIM, HDIM);

  // fused: h = silu(g)*u in-place into gbuf + down-router top2
  swiglu_router<<<T_TOK/4, 256, 0, stream>>>(gbuf, ubuf, drt, topi_d, topw_d);
  build_perm<<<NEXP, 256, 0, stream>>>(topi_d, topw_d, offs_d, ptok_d, pw_d);

  moe_gemm_down<<<dim3(HDIM/BN, T_TOK/BM, NEXP), 256, 0, stream>>>(
      gbuf, wd_hi, offs_d, ptok_d, pw_d, out);
}

// Round 6
// 1779.135 us; speedup vs baseline: 2.5464x; 1.0016x over previous
//
#include <hip/hip_runtime.h>
#include <stdint.h>
#include <stdio.h>

#define T_TOK 8192
#define HDIM  1024
#define IDIM  3584
#define NEXP  8
#define NPAIR (T_TOK*2)
#define BM 128
#define BN 128
#define BK 32

typedef float          f32x4 __attribute__((ext_vector_type(4)));
typedef short          s16x8 __attribute__((ext_vector_type(8)));
typedef unsigned short u16x4 __attribute__((ext_vector_type(4)));
typedef unsigned short u16x8 __attribute__((ext_vector_type(8)));

__device__ __forceinline__ unsigned short f2bf_rne(float f) {
  unsigned u = __float_as_uint(f);
  u += 0x7FFFu + ((u >> 16) & 1u);
  return (unsigned short)(u >> 16);
}
__device__ __forceinline__ float bf2f(unsigned short h) {
  return __uint_as_float(((unsigned)h) << 16);
}

__device__ __forceinline__ void gld16(const void* gsrc, void* ldst) {
  typedef const unsigned int __attribute__((address_space(1))) GU;
  typedef unsigned int       __attribute__((address_space(3))) LU;
  __builtin_amdgcn_global_load_lds((GU*)(unsigned long long)gsrc,
                                   (LU*)(unsigned int)(unsigned long long)ldst,
                                   16, 0, 0);
}

// ================= K1: split f32 -> (hi, lo) bf16 =================
__global__ void split_hilo(const float* __restrict__ in,
                           unsigned short* __restrict__ hi,
                           unsigned short* __restrict__ lo, int n4) {
  int i = blockIdx.x*blockDim.x + threadIdx.x;
  int s = gridDim.x*blockDim.x;
  for (; i < n4; i += s) {
    f32x4 v = ((const f32x4*)in)[i];
    u16x4 h, l;
#pragma unroll
    for (int j = 0; j < 4; j++) {
      float f = v[j];
      unsigned short hb = f2bf_rne(f);
      h[j] = hb;
      l[j] = f2bf_rne(f - bf2f(hb));
    }
    ((u16x4*)hi)[i] = h;
    ((u16x4*)lo)[i] = l;
  }
}

// ===== K2: transpose W [E][K][N] f32 -> Wt [E][N][K] bf16 hi (+lo optional)
__global__ void transpose_split(const float* __restrict__ W,
                                unsigned short* __restrict__ hi,
                                unsigned short* __restrict__ lo,
                                int K, int N) {
  __shared__ float tile[32][33];
  long base = (long)blockIdx.z * K * N;
  int n0 = blockIdx.x*32, k0 = blockIdx.y*32;
  int tx = threadIdx.x, ty = threadIdx.y; // 32 x 8
#pragma unroll
  for (int r = 0; r < 4; r++)
    tile[ty+8*r][tx] = W[base + (long)(k0+ty+8*r)*N + n0 + tx];
  __syncthreads();
#pragma unroll
  for (int r = 0; r < 4; r++) {
    float f = tile[tx][ty+8*r];
    long o = base + (long)(n0+ty+8*r)*K + k0 + tx;
    unsigned short hb = f2bf_rne(f);
    hi[o] = hb;
    if (lo) lo[o] = f2bf_rne(f - bf2f(hb));
  }
}

// ---- shared top-2 helper (stable, lowest-index tie-break like lax.top_k)
__device__ __forceinline__ void top2_write(const float* acc, int t,
                                           int* __restrict__ topi,
                                           float* __restrict__ topw) {
  int i0 = 0; float l0 = acc[0];
#pragma unroll
  for (int e = 1; e < NEXP; e++) if (acc[e] > l0) { l0 = acc[e]; i0 = e; }
  int i1 = -1; float l1 = -3.4e38f;
#pragma unroll
  for (int e = 0; e < NEXP; e++) if (e != i0 && acc[e] > l1) { l1 = acc[e]; i1 = e; }
  float w0 = 1.f/(1.f + expf(l1 - l0));
  float w1 = 1.f/(1.f + expf(l0 - l1));
  topi[2*t]   = i0; topi[2*t+1] = i1;
  topw[2*t]   = w0; topw[2*t+1] = w1;
}

// ===== K3: fused gate+up router (one pass over x) =========================
__global__ __launch_bounds__(256) void router2_topk(
    const float* __restrict__ X,
    const float* __restrict__ RWg, const float* __restrict__ RWu,
    int* __restrict__ tig, float* __restrict__ twg,
    int* __restrict__ tiu, float* __restrict__ twu) {
  int lane = threadIdx.x & 63;
  int t = blockIdx.x*4 + (threadIdx.x>>6);
  const f32x4* xr = (const f32x4*)(X + (long)t*HDIM);
  float ag[NEXP], au[NEXP];
#pragma unroll
  for (int e = 0; e < NEXP; e++) { ag[e] = 0.f; au[e] = 0.f; }
#pragma unroll
  for (int it = 0; it < HDIM/4/64; it++) {   // 4
    int c4 = it*64 + lane;
    f32x4 xv = xr[c4];
#pragma unroll
    for (int j = 0; j < 4; j++) {
      const float* wg = RWg + (long)(c4*4+j)*NEXP;
      const float* wu = RWu + (long)(c4*4+j)*NEXP;
#pragma unroll
      for (int e = 0; e < NEXP; e++) { ag[e] += xv[j]*wg[e]; au[e] += xv[j]*wu[e]; }
    }
  }
#pragma unroll
  for (int e = 0; e < NEXP; e++) {
    float vg = ag[e], vu = au[e];
#pragma unroll
    for (int o = 1; o < 64; o <<= 1) { vg += __shfl_xor(vg, o); vu += __shfl_xor(vu, o); }
    ag[e] = vg; au[e] = vu;
  }
  if (lane == 0) { top2_write(ag, t, tig, twg); top2_write(au, t, tiu, twu); }
}

// ===== K4: deterministic stable per-expert compaction (1 block per expert)
__global__ __launch_bounds__(256) void build_perm(const int* __restrict__ topi,
                                                  const float* __restrict__ topw,
                                                  int* __restrict__ offs,
                                                  int* __restrict__ ptok,
                                                  float* __restrict__ pw) {
  int e = blockIdx.x;
  int tid = threadIdx.x, lane = tid & 63, wv = tid >> 6;
  __shared__ int cnt[NEXP];
  __shared__ int wsum[4];
  if (tid < NEXP) cnt[tid] = 0;
  __syncthreads();
  for (int p = tid; p < NPAIR; p += 256) atomicAdd(&cnt[topi[p]], 1);
  __syncthreads();
  int base = 0;
#pragma unroll
  for (int e2 = 0; e2 < NEXP; e2++) if (e2 < e) base += cnt[e2];
  if (tid == 0) { offs[e] = base; if (e == NEXP-1) offs[NEXP] = base + cnt[e]; }
  for (int p0 = 0; p0 < NPAIR; p0 += 256) {
    int p = p0 + tid;
    bool m = (topi[p] == e);
    unsigned long long b = __ballot(m);
    int lp = __popcll(b & ((1ull << lane) - 1ull));
    if (lane == 0) wsum[wv] = __popcll(b);
    __syncthreads();
    int woff = 0;
#pragma unroll
    for (int w2 = 0; w2 < 4; w2++) if (w2 < wv) woff += wsum[w2];
    int tot = wsum[0] + wsum[1] + wsum[2] + wsum[3];
    if (m) { int dst = base + woff + lp; ptok[dst] = p >> 1; pw[dst] = topw[p]; }
    base += tot;
    __syncthreads();
  }
}

// ===== K5: gathered MoE GEMM, 3-term bf16 split ===========================
// (Ahi+Alo)@(Bhi+Blo) minus the lo@lo term (~2^-18 relative — negligible).
// m97 single-buffer structure (known 530us @ 4-term); staging unchanged.
__global__ __launch_bounds__(256) void moe_gemm3(
    const unsigned short* __restrict__ Ahi, const unsigned short* __restrict__ Alo,
    const unsigned short* __restrict__ Bhi, const unsigned short* __restrict__ Blo,
    const int* __restrict__ offs, const int* __restrict__ ptok,
    const float* __restrict__ pw, float* __restrict__ out, int K, int N)
{
  const int e = blockIdx.z;
  const int beg = offs[e];
  const int cnt = offs[e+1] - beg;
  const int m0 = blockIdx.y * BM;   // NO swizzle (round-3 lesson: early-return
  if (m0 >= cnt) return;            // tails must stay spread across XCDs)
  const int n0 = blockIdx.x * BN;

  __shared__ unsigned short Ah[BM*BK], Al[BM*BK], Bh[BN*BK], Bl[BN*BK];
  __shared__ int   stok[BM];
  __shared__ float swt[BM];

  const int tid = threadIdx.x, lane = tid & 63, wv = tid >> 6;
  if (tid < BM) {
    int i = m0 + tid;
    stok[tid] = ptok[beg + (i < cnt ? i : 0)];
    swt[tid]  = (i < cnt) ? pw[beg + i] : 0.f;
  }
  __syncthreads();

  const int srow = lane >> 2;
  const int scol = (lane & 3) * 8;
  const int r0 = (wv*2+0)*16 + srow;
  const int r1 = (wv*2+1)*16 + srow;
  const long a0 = (long)stok[r0]*K + scol;
  const long a1 = (long)stok[r1]*K + scol;
  const long b0 = ((long)e*N + n0 + r0)*K + scol;
  const long b1 = ((long)e*N + n0 + r1)*K + scol;
  unsigned short* dA0  = &Ah[(wv*2+0)*16*BK];
  unsigned short* dA1  = &Ah[(wv*2+1)*16*BK];
  unsigned short* dAl0 = &Al[(wv*2+0)*16*BK];
  unsigned short* dAl1 = &Al[(wv*2+1)*16*BK];
  unsigned short* dB0  = &Bh[(wv*2+0)*16*BK];
  unsigned short* dB1  = &Bh[(wv*2+1)*16*BK];
  unsigned short* dBl0 = &Bl[(wv*2+0)*16*BK];
  unsigned short* dBl1 = &Bl[(wv*2+1)*16*BK];

  f32x4 zero = {0.f, 0.f, 0.f, 0.f};
  f32x4 acc[4][4];
#pragma unroll
  for (int i = 0; i < 4; i++)
#pragma unroll
    for (int j = 0; j < 4; j++) acc[i][j] = zero;

  const int arow = (wv>>1)*64, bcol = (wv&1)*64;
  const int fl = lane & 15, fg = lane >> 4;

  for (int kk = 0; kk < K; kk += BK) {
    __syncthreads();
    gld16(Ahi + a0 + kk, dA0);  gld16(Ahi + a1 + kk, dA1);
    gld16(Alo + a0 + kk, dAl0); gld16(Alo + a1 + kk, dAl1);
    gld16(Bhi + b0 + kk, dB0);  gld16(Bhi + b1 + kk, dB1);
    gld16(Blo + b0 + kk, dBl0); gld16(Blo + b1 + kk, dBl1);
    asm volatile("s_waitcnt vmcnt(0)" ::: "memory");
    __syncthreads();

    s16x8 ahf[4], alf[4], bhf[4], blf[4];
#pragma unroll
    for (int i = 0; i < 4; i++) {
      ahf[i] = *(const s16x8*)&Ah[(arow + i*16 + fl)*BK + fg*8];
      alf[i] = *(const s16x8*)&Al[(arow + i*16 + fl)*BK + fg*8];
      bhf[i] = *(const s16x8*)&Bh[(bcol + i*16 + fl)*BK + fg*8];
      blf[i] = *(const s16x8*)&Bl[(bcol + i*16 + fl)*BK + fg*8];
    }
#pragma unroll
    for (int i = 0; i < 4; i++)
#pragma unroll
      for (int j = 0; j < 4; j++) {
        acc[i][j] = __builtin_amdgcn_mfma_f32_16x16x32_bf16(ahf[i], bhf[j], acc[i][j], 0,0,0);
        acc[i][j] = __builtin_amdgcn_mfma_f32_16x16x32_bf16(alf[i], bhf[j], acc[i][j], 0,0,0);
        acc[i][j] = __builtin_amdgcn_mfma_f32_16x16x32_bf16(ahf[i], blf[j], acc[i][j], 0,0,0);
        // lo@lo term dropped (round-5): ~2^-18 relative on h
      }
  }

  // epilogue: C/D map col=lane&15, row=(lane>>4)*4+r  [m89/m91-verified]
#pragma unroll
  for (int i = 0; i < 4; i++)
#pragma unroll
    for (int r = 0; r < 4; r++) {
      int lrow = arow + i*16 + fg*4 + r;
      if (m0 + lrow < cnt) {
        float wt = swt[lrow];
        long ob = (long)stok[lrow]*N + n0 + bcol + fl;
#pragma unroll
        for (int j = 0; j < 4; j++)
          atomicAdd(&out[ob + j*16], wt * acc[i][j][r]);
      }
    }
}

// ===== K6: fused SwiGLU + down-router (h in-place into g, one pass) =======
__global__ __launch_bounds__(256) void swiglu_router(
    float* __restrict__ g, const float* __restrict__ u,
    const float* __restrict__ RW,           // down router [IDIM][NEXP]
    int* __restrict__ topi, float* __restrict__ topw) {
  int lane = threadIdx.x & 63;
  int t = blockIdx.x*4 + (threadIdx.x>>6);
  f32x4*       gr = (f32x4*)(g + (long)t*IDIM);
  const f32x4* ur = (const f32x4*)(u + (long)t*IDIM);
  float acc[NEXP];
#pragma unroll
  for (int e = 0; e < NEXP; e++) acc[e] = 0.f;
#pragma unroll
  for (int it = 0; it < IDIM/4/64; it++) {   // 14
    int c4 = it*64 + lane;
    f32x4 gv = gr[c4], uv = ur[c4], hv;
#pragma unroll
    for (int j = 0; j < 4; j++) {
      float x = gv[j];
      hv[j] = x * uv[j] / (1.f + expf(-x));
    }
    gr[c4] = hv;
#pragma unroll
    for (int j = 0; j < 4; j++) {
      const float* wr = RW + (long)(c4*4+j)*NEXP;
#pragma unroll
      for (int e = 0; e < NEXP; e++) acc[e] += hv[j]*wr[e];
    }
  }
#pragma unroll
  for (int e = 0; e < NEXP; e++) {
    float v = acc[e];
#pragma unroll
    for (int o = 1; o < 64; o <<= 1) v += __shfl_xor(v, o);
    acc[e] = v;
  }
  if (lane == 0) top2_write(acc, t, topi, topw);
}

// ===== K7: down GEMM, 1-term: A = bf16(h), B = Wd_hi bf16 =================
// Routing already decided on exact h; dropping h_lo only perturbs VALUES
// (~1e-2 worst-case vs 3.2e-2 threshold). T14: next A-tile's f32 loads are
// issued right after the barrier so HBM latency hides under MFMA.
__global__ __launch_bounds__(256) void moe_gemm_down(
    const float* __restrict__ Hf, const unsigned short* __restrict__ Bw,
    const int* __restrict__ offs, const int* __restrict__ ptok,
    const float* __restrict__ pw, float* __restrict__ out)
{
  const int K = IDIM, N = HDIM;
  const int e = blockIdx.z;
  const int beg = offs[e];
  const int cnt = offs[e+1] - beg;
  const int m0 = blockIdx.y * BM;   // NO swizzle
  if (m0 >= cnt) return;
  const int n0 = blockIdx.x * BN;

  __shared__ unsigned short Ah[BM*BK], Bh[BN*BK];
  __shared__ int   stok[BM];
  __shared__ float swt[BM];

  const int tid = threadIdx.x, lane = tid & 63, wv = tid >> 6;
  if (tid < BM) {
    int i = m0 + tid;
    stok[tid] = ptok[beg + (i < cnt ? i : 0)];
    swt[tid]  = (i < cnt) ? pw[beg + i] : 0.f;
  }
  __syncthreads();

  // A path: each thread owns half a row (16 f32 -> 16 bf16)
  const int arw = tid >> 1, half = tid & 1;
  const float* asrc = Hf + (long)stok[arw]*K + half*16;
  const int awoff = arw*BK + half*16;

  // B path: gld16 staging
  const int srow = lane >> 2, scol = (lane & 3)*8;
  const int r0 = (wv*2+0)*16 + srow, r1 = (wv*2+1)*16 + srow;
  const long b0 = ((long)e*N + n0 + r0)*K + scol;
  const long b1 = ((long)e*N + n0 + r1)*K + scol;
  unsigned short* dB0 = &Bh[(wv*2+0)*16*BK];
  unsigned short* dB1 = &Bh[(wv*2+1)*16*BK];

  f32x4 zero = {0.f,0.f,0.f,0.f};
  f32x4 acc[4][4];
#pragma unroll
  for (int i = 0; i < 4; i++)
#pragma unroll
    for (int j = 0; j < 4; j++) acc[i][j] = zero;

  const int arow = (wv>>1)*64, bcol = (wv&1)*64;
  const int fl = lane & 15, fg = lane >> 4;

  f32x4 p0, p1, p2, p3;
#define LOADA(kk) do {                        \
    p0 = ((const f32x4*)(asrc + (kk)))[0];    \
    p1 = ((const f32x4*)(asrc + (kk)))[1];    \
    p2 = ((const f32x4*)(asrc + (kk)))[2];    \
    p3 = ((const f32x4*)(asrc + (kk)))[3];    \
  } while (0)

  LOADA(0);  // prologue: A regs for tile 0

  for (int kk = 0; kk < K; kk += BK) {
    __syncthreads();                 // everyone done reading LDS (prev step)
    gld16(Bw + b0 + kk, dB0);
    gld16(Bw + b1 + kk, dB1);
    // cvt regs -> bf16, write A tile (data loaded during prev step's MFMA)
    u16x8 ha, hb2;
    ha[0]=f2bf_rne(p0[0]); ha[1]=f2bf_rne(p0[1]); ha[2]=f2bf_rne(p0[2]); ha[3]=f2bf_rne(p0[3]);
    ha[4]=f2bf_rne(p1[0]); ha[5]=f2bf_rne(p1[1]); ha[6]=f2bf_rne(p1[2]); ha[7]=f2bf_rne(p1[3]);
    hb2[0]=f2bf_rne(p2[0]); hb2[1]=f2bf_rne(p2[1]); hb2[2]=f2bf_rne(p2[2]); hb2[3]=f2bf_rne(p2[3]);
    hb2[4]=f2bf_rne(p3[0]); hb2[5]=f2bf_rne(p3[1]); hb2[6]=f2bf_rne(p3[2]); hb2[7]=f2bf_rne(p3[3]);
    *(u16x8*)&Ah[awoff]   = ha;
    *(u16x8*)&Ah[awoff+8] = hb2;
    asm volatile("s_waitcnt vmcnt(0)" ::: "memory");
    __syncthreads();                 // B landed + A written

    if (kk + BK < K) LOADA(kk + BK); // T14: issue next A loads under MFMA

    s16x8 ahf[4], bhf[4];
#pragma unroll
    for (int i = 0; i < 4; i++) {
      ahf[i] = *(const s16x8*)&Ah[(arow + i*16 + fl)*BK + fg*8];
      bhf[i] = *(const s16x8*)&Bh[(bcol + i*16 + fl)*BK + fg*8];
    }
#pragma unroll
    for (int i = 0; i < 4; i++)
#pragma unroll
      for (int j = 0; j < 4; j++)
        acc[i][j] = __builtin_amdgcn_mfma_f32_16x16x32_bf16(ahf[i], bhf[j], acc[i][j], 0,0,0);
  }
#undef LOADA

#pragma unroll
  for (int i = 0; i < 4; i++)
#pragma unroll
    for (int r = 0; r < 4; r++) {
      int lrow = arow + i*16 + fg*4 + r;
      if (m0 + lrow < cnt) {
        float wt = swt[lrow];
        long ob = (long)stok[lrow]*N + n0 + bcol + fl;
#pragma unroll
        for (int j = 0; j < 4; j++)
          atomicAdd(&out[ob + j*16], wt * acc[i][j][r]);
      }
    }
}

// ========================== host launcher =================================
// Workspace aliasing (448 MiB avail, peak ~387 MB):
//   ubuf  aliases [wg_hi, wg_lo] — first written AFTER gate GEMM (last wg reader)
//   wd_hi aliases [wu_hi, ...]   — transposed AFTER up GEMM (last wu reader)
extern "C" void kernel_launch(void* const* d_in, const int* in_sizes, int n_in,
                              void* d_out, int out_size, void* d_ws, size_t ws_size,
                              hipStream_t stream)
{
  (void)in_sizes; (void)n_in;
  const float* x   = (const float*)d_in[0];
  const float* grt = (const float*)d_in[1];
  const float* gex = (const float*)d_in[2];
  const float* urt = (const float*)d_in[3];
  const float* uex = (const float*)d_in[4];
  const float* drt = (const float*)d_in[5];
  const float* dex = (const float*)d_in[6];
  float* out = (float*)d_out;

  char* base = (char*)d_ws;
  size_t off = 0;
  auto alloc = [&](size_t b) -> void* {
    void* r = base + off;
    off = (off + b + 255) & ~(size_t)255;
    return r;
  };
  const size_t szXH = (size_t)T_TOK*HDIM*2;
  const size_t szW  = (size_t)NEXP*HDIM*IDIM*2;
  const size_t szGI = (size_t)T_TOK*IDIM*4;

  unsigned short* xhi   = (unsigned short*)alloc(szXH);
  unsigned short* xlo   = (unsigned short*)alloc(szXH);
  unsigned short* wg_hi = (unsigned short*)alloc(szW);   // later: ubuf (f32)
  unsigned short* wg_lo = (unsigned short*)alloc(szW);
  unsigned short* wu_hi = (unsigned short*)alloc(szW);   // later: wd_hi
  unsigned short* wu_lo = (unsigned short*)alloc(szW);
  float* gbuf = (float*)alloc(szGI);
  int*   topi_g = (int*)alloc(NPAIR*4);  float* topw_g = (float*)alloc(NPAIR*4);
  int*   topi_u = (int*)alloc(NPAIR*4);  float* topw_u = (float*)alloc(NPAIR*4);
  int*   topi_d = (int*)alloc(NPAIR*4);  float* topw_d = (float*)alloc(NPAIR*4);
  int* offs_g = (int*)alloc(64);
  int* offs_u = (int*)alloc(64);
  int* offs_d = (int*)alloc(64);
  int*   ptok_g = (int*)alloc(NPAIR*4);  float* pw_g = (float*)alloc(NPAIR*4);
  int*   ptok_u = (int*)alloc(NPAIR*4);  float* pw_u = (float*)alloc(NPAIR*4);
  int*   ptok_d = (int*)alloc(NPAIR*4);  float* pw_d = (float*)alloc(NPAIR*4);

  float*          ubuf  = (float*)wg_hi;
  unsigned short* wd_hi = wu_hi;

  if (off > ws_size) {
    fprintf(stderr, "[moe] ws too small: need %zu bytes, have %zu\n", off, ws_size);
    hipMemsetAsync(d_out, 0, (size_t)out_size*sizeof(float), stream);
    return;
  }

  hipMemsetAsync(gbuf, 0, szGI, stream);
  hipMemsetAsync(d_out, 0, (size_t)out_size*sizeof(float), stream);

  split_hilo<<<2048, 256, 0, stream>>>(x, xhi, xlo, T_TOK*HDIM/4);
  transpose_split<<<dim3(IDIM/32, HDIM/32, NEXP), dim3(32,8), 0, stream>>>(gex, wg_hi, wg_lo, HDIM, IDIM);
  transpose_split<<<dim3(IDIM/32, HDIM/32, NEXP), dim3(32,8), 0, stream>>>(uex, wu_hi, wu_lo, HDIM, IDIM);
  router2_topk<<<T_TOK/4, 256, 0, stream>>>(x, grt, urt, topi_g, topw_g, topi_u, topw_u);
  build_perm<<<NEXP, 256, 0, stream>>>(topi_g, topw_g, offs_g, ptok_g, pw_g);
  build_perm<<<NEXP, 256, 0, stream>>>(topi_u, topw_u, offs_u, ptok_u, pw_u);

  // gate GEMM (last reader of wg region)
  moe_gemm3<<<dim3(IDIM/BN, T_TOK/BM, NEXP), 256, 0, stream>>>(
      xhi, xlo, wg_hi, wg_lo, offs_g, ptok_g, pw_g, gbuf, HDIM, IDIM);

  // wg region dead -> ubuf
  hipMemsetAsync(ubuf, 0, szGI, stream);
  moe_gemm3<<<dim3(IDIM/BN, T_TOK/BM, NEXP), 256, 0, stream>>>(
      xhi, xlo, wu_hi, wu_lo, offs_u, ptok_u, pw_u, ubuf, HDIM, IDIM);

  // wu region dead -> wd_hi
  transpose_split<<<dim3(HDIM/32, IDIM/32, NEXP), dim3(32,8), 0, stream>>>(dex, wd_hi, nullptr, IDIM, HDIM);

  // fused: h = silu(g)*u in-place into gbuf + down-router top2
  swiglu_router<<<T_TOK/4, 256, 0, stream>>>(gbuf, ubuf, drt, topi_d, topw_d);
  build_perm<<<NEXP, 256, 0, stream>>>(topi_d, topw_d, offs_d, ptok_d, pw_d);

  moe_gemm_down<<<dim3(HDIM/BN, T_TOK/BM, NEXP), 256, 0, stream>>>(
      gbuf, wd_hi, offs_d, ptok_d, pw_d, out);
}